// Round 4
// baseline (14937.482 us; speedup 1.0000x reference)
//
#include <hip/hip_runtime.h>
#include <hip/hip_bf16.h>
#include <hip/hip_fp16.h>

#define NN 262144
#define EE 1048576
#define GG 8192
#define HH 128
#define FAc 9
#define FBc 3
#define VAc 64
#define VBc 8

// ---- bf16 <-> f32 bit helpers (RNE) ----
__device__ __forceinline__ float b2f(ushort b) {
    return __uint_as_float(((unsigned)b) << 16);
}
__device__ __forceinline__ ushort f2b(float f) {
    unsigned u = __float_as_uint(f);
    unsigned r = (u + 0x7FFFu + ((u >> 16) & 1u)) >> 16;
    return (ushort)r;
}
// ---- fp16 <-> f32 helpers ----
__device__ __forceinline__ float h2f(ushort u) {
    __half h; *(ushort*)&h = u; return __half2float(h);
}
__device__ __forceinline__ ushort f2h(float f) {
    __half h = __float2half_rn(f); return *(ushort*)&h;
}

template <bool HBF>
__device__ __forceinline__ float4 load4h(const void* p, size_t off) {
    if (HBF) {
        ushort4 u = *(const ushort4*)((const ushort*)p + off);
        return make_float4(b2f(u.x), b2f(u.y), b2f(u.z), b2f(u.w));
    } else {
        return *(const float4*)((const float*)p + off);
    }
}
template <bool HBF>
__device__ __forceinline__ void store4h(void* p, size_t off, float4 v) {
    if (HBF) {
        ushort4 o; o.x = f2b(v.x); o.y = f2b(v.y); o.z = f2b(v.z); o.w = f2b(v.w);
        *(ushort4*)((ushort*)p + off) = o;
    } else {
        *(float4*)((float*)p + off) = v;
    }
}

// ---------------- zero fill (graph-capture-safe memset) ----------------
__global__ void k_zero(float* __restrict__ p) {
    size_t i = (size_t)(blockIdx.x * 256 + threadIdx.x) * 4;
    *(float4*)(p + i) = make_float4(0.f, 0.f, 0.f, 0.f);
}

// ---------------- atom encoder: h[n][c] = sum_f atom_emb[f][x[n][f]][c] ----------------
template <bool HBF>
__global__ void k_atom(const int* __restrict__ x, const float* __restrict__ emb,
                       void* __restrict__ h) {
    int t = blockIdx.x * 256 + threadIdx.x;
    int n = t >> 5, c = (t & 31) << 2;
    if (n >= NN) return;
    float4 a = make_float4(0.f, 0.f, 0.f, 0.f);
#pragma unroll
    for (int f = 0; f < FAc; ++f) {
        int v = x[n * FAc + f];
        float4 e = *(const float4*)(emb + ((size_t)(f * VAc + v)) * HH + c);
        a.x += e.x; a.y += e.y; a.z += e.z; a.w += e.w;
    }
    store4h<HBF>(h, (size_t)n * HH + c, a);
}

// ---------------- vn init ----------------
__global__ void k_init_vn(const float* __restrict__ vn_emb, float* __restrict__ vn) {
    int t = blockIdx.x * 256 + threadIdx.x;
    int g = t >> 5, c = (t & 31) << 2;
    *(float4*)(vn + (size_t)g * HH + c) = *(const float4*)(vn_emb + c);
}

// ---------------- h(f32) += vn[batch]; also write fp16 snapshot ----------------
__global__ void k_addvn_snap(float* __restrict__ h, ushort* __restrict__ hh,
                             const float* __restrict__ vn, const int* __restrict__ batch) {
    int t = blockIdx.x * 256 + threadIdx.x;
    int n = t >> 5, c = (t & 31) << 2;
    size_t off = (size_t)n * HH + c;
    float4 hv = *(const float4*)(h + off);
    float4 vv = *(const float4*)(vn + (size_t)batch[n] * HH + c);
    hv.x += vv.x; hv.y += vv.y; hv.z += vv.z; hv.w += vv.w;
    *(float4*)(h + off) = hv;
    ushort4 s; s.x = f2h(hv.x); s.y = f2h(hv.y); s.z = f2h(hv.z); s.w = f2h(hv.w);
    *(ushort4*)(hh + off) = s;
}

// ---- bf16-path addvn (fallback) ----
template <bool HBF>
__global__ void k_addvn(void* __restrict__ h, const float* __restrict__ vn,
                        const int* __restrict__ batch) {
    int t = blockIdx.x * 256 + threadIdx.x;
    int n = t >> 5, c = (t & 31) << 2;
    size_t off = (size_t)n * HH + c;
    float4 hv = load4h<HBF>(h, off);
    float4 vv = *(const float4*)(vn + (size_t)batch[n] * HH + c);
    hv.x += vv.x; hv.y += vv.y; hv.z += vv.z; hv.w += vv.w;
    store4h<HBF>(h, off, hv);
}

// ------- bucketed edge pass: for edges with dst in bucket, agg_chunk[dst-base] += relu(hh[src]+e) -------
__global__ void k_edge_b(const ushort* __restrict__ hh, const int* __restrict__ ei,
                         const int* __restrict__ ea, const float* __restrict__ bemb,
                         float* __restrict__ aggc, int bucket, int shift) {
    int t = blockIdx.x * 256 + threadIdx.x;
    int e = t >> 5, c = (t & 31) << 2;
    if (e >= EE) return;
    int dst = ei[EE + e];
    if ((dst >> shift) != bucket) return;
    int src = ei[e];
    int a0 = ea[e * 3 + 0], a1 = ea[e * 3 + 1], a2 = ea[e * 3 + 2];
    float4 b0 = *(const float4*)(bemb + ((size_t)(0 * VBc + a0)) * HH + c);
    float4 b1 = *(const float4*)(bemb + ((size_t)(1 * VBc + a1)) * HH + c);
    float4 b2 = *(const float4*)(bemb + ((size_t)(2 * VBc + a2)) * HH + c);
    ushort4 hu = *(const ushort4*)(hh + (size_t)src * HH + c);
    float m0 = fmaxf(h2f(hu.x) + b0.x + b1.x + b2.x, 0.f);
    float m1 = fmaxf(h2f(hu.y) + b0.y + b1.y + b2.y, 0.f);
    float m2 = fmaxf(h2f(hu.z) + b0.z + b1.z + b2.z, 0.f);
    float m3 = fmaxf(h2f(hu.w) + b0.w + b1.w + b2.w, 0.f);
    float* p = aggc + (size_t)(dst - (bucket << shift)) * HH + c;
    atomicAdd(p + 0, m0);
    atomicAdd(p + 1, m1);
    atomicAdd(p + 2, m2);
    atomicAdd(p + 3, m3);
}

// ---- fallback full-N edge pass (bf16 h) ----
template <bool HBF>
__global__ void k_edge(const void* __restrict__ h, const int* __restrict__ ei,
                       const int* __restrict__ ea, const float* __restrict__ bemb,
                       float* __restrict__ agg) {
    int t = blockIdx.x * 256 + threadIdx.x;
    int e = t >> 5, c = (t & 31) << 2;
    if (e >= EE) return;
    int src = ei[e], dst = ei[EE + e];
    int a0 = ea[e * 3 + 0], a1 = ea[e * 3 + 1], a2 = ea[e * 3 + 2];
    float4 b0 = *(const float4*)(bemb + ((size_t)(0 * VBc + a0)) * HH + c);
    float4 b1 = *(const float4*)(bemb + ((size_t)(1 * VBc + a1)) * HH + c);
    float4 b2 = *(const float4*)(bemb + ((size_t)(2 * VBc + a2)) * HH + c);
    float4 hv = load4h<HBF>(h, (size_t)src * HH + c);
    float m0 = fmaxf(hv.x + b0.x + b1.x + b2.x, 0.f);
    float m1 = fmaxf(hv.y + b0.y + b1.y + b2.y, 0.f);
    float m2 = fmaxf(hv.z + b0.z + b1.z + b2.z, 0.f);
    float m3 = fmaxf(hv.w + b0.w + b1.w + b2.w, 0.f);
    float* p = agg + (size_t)dst * HH + c;
    atomicAdd(p + 0, m0);
    atomicAdd(p + 1, m1);
    atomicAdd(p + 2, m2);
    atomicAdd(p + 3, m3);
}

// ---------------- tiled f32 GEMM, 64x64 tile, BK=32, fused epilogues ----------------
enum { A_PLAIN = 0, A_Z = 1 };
enum { E_BIAS = 0, E_BNRELU = 1, E_POOL = 2 };

template <bool ABF, int AMODE, int EMODE, bool OBF>
__global__ void __launch_bounds__(256)
gemm_k(const void* __restrict__ Av, const float* __restrict__ A2,
       const float* __restrict__ B,
       const float* __restrict__ bias,
       const float* __restrict__ g_, const float* __restrict__ b_,
       const float* __restrict__ m_, const float* __restrict__ v_,
       const float* __restrict__ addrow, const int* __restrict__ batch,
       const float* __restrict__ eps_ptr,
       void* __restrict__ outv, int K, int Nc) {
    __shared__ float As[64][33];
    __shared__ float Bs[32][64];
    const int tid = threadIdx.x;
    const int row0 = blockIdx.x * 64;
    const int col0 = blockIdx.y * 64;
    float eps1 = 0.f;
    if (AMODE == A_Z) eps1 = 1.f + eps_ptr[0];
    float acc[4][4] = {};
    const int tx = tid & 15, ty = tid >> 4;

    for (int k0 = 0; k0 < K; k0 += 32) {
#pragma unroll
        for (int p = 0; p < 2; ++p) {
            int idx = p * 256 + tid;
            {   // A tile: 64 rows x 32 cols
                int r = idx >> 3, c = (idx & 7) << 2;
                size_t aoff = (size_t)(row0 + r) * K + k0 + c;
                float4 va = load4h<ABF>(Av, aoff);
                if (AMODE == A_Z) {
                    float4 vg = *(const float4*)(A2 + aoff);
                    va.x = eps1 * va.x + vg.x; va.y = eps1 * va.y + vg.y;
                    va.z = eps1 * va.z + vg.z; va.w = eps1 * va.w + vg.w;
                }
                As[r][c + 0] = va.x; As[r][c + 1] = va.y;
                As[r][c + 2] = va.z; As[r][c + 3] = va.w;
            }
            {   // B tile: 32 rows x 64 cols (B always f32 weights)
                int kr = idx >> 4, cc = (idx & 15) << 2;
                *(float4*)&Bs[kr][cc] =
                    *(const float4*)(B + (size_t)(k0 + kr) * Nc + col0 + cc);
            }
        }
        __syncthreads();
#pragma unroll
        for (int k = 0; k < 32; ++k) {
            float4 bv = *(const float4*)&Bs[k][tx << 2];
            float a0 = As[ty * 4 + 0][k];
            float a1 = As[ty * 4 + 1][k];
            float a2 = As[ty * 4 + 2][k];
            float a3 = As[ty * 4 + 3][k];
            acc[0][0] += a0 * bv.x; acc[0][1] += a0 * bv.y; acc[0][2] += a0 * bv.z; acc[0][3] += a0 * bv.w;
            acc[1][0] += a1 * bv.x; acc[1][1] += a1 * bv.y; acc[1][2] += a1 * bv.z; acc[1][3] += a1 * bv.w;
            acc[2][0] += a2 * bv.x; acc[2][1] += a2 * bv.y; acc[2][2] += a2 * bv.z; acc[2][3] += a2 * bv.w;
            acc[3][0] += a3 * bv.x; acc[3][1] += a3 * bv.y; acc[3][2] += a3 * bv.z; acc[3][3] += a3 * bv.w;
        }
        __syncthreads();
    }

#pragma unroll
    for (int j = 0; j < 4; ++j) {
        int gr = row0 + ty * 4 + j;
        float vals[4];
        int gg = 0;
        if (EMODE == E_POOL) gg = batch[gr];
#pragma unroll
        for (int l = 0; l < 4; ++l) {
            int gc = col0 + (tx << 2) + l;
            float val = acc[j][l];
            if (EMODE == E_BIAS) {
                vals[l] = val + bias[gc];
            } else if (EMODE == E_BNRELU) {
                float y = val + bias[gc];
                float s = g_[gc] * rsqrtf(v_[gc] + 1e-5f);
                y = (y - m_[gc]) * s + b_[gc];
                vals[l] = fmaxf(y, 0.f);
            } else {  // E_POOL
                float y = val + addrow[(size_t)gg * Nc + gc];
                float s = g_[gc] * rsqrtf(v_[gc] + 1e-5f);
                y = (y - m_[gc]) * s + b_[gc];
                atomicAdd((float*)outv + (size_t)gg * Nc + gc, fmaxf(y, 0.f));
            }
        }
        if (EMODE != E_POOL) {
            size_t ooff = (size_t)gr * Nc + col0 + (tx << 2);
            store4h<OBF>(outv, ooff, make_float4(vals[0], vals[1], vals[2], vals[3]));
        }
    }
}

// ---------------- final head ----------------
__global__ void k_final(const float* __restrict__ vn, const float* __restrict__ pW1,
                        const float* __restrict__ pb1, const float* __restrict__ pW2,
                        const float* __restrict__ pb2, float* __restrict__ out) {
    int g = blockIdx.x;
    int j = threadIdx.x;  // 128 threads
    __shared__ float vrow[HH];
    __shared__ float red[HH];
    vrow[j] = vn[(size_t)g * HH + j];
    __syncthreads();
    float acc = pb1[j];
    for (int k = 0; k < HH; ++k) acc = fmaf(vrow[k], pW1[k * HH + j], acc);
    red[j] = fmaxf(acc, 0.f) * pW2[j];
    __syncthreads();
    for (int s = 64; s > 0; s >>= 1) {
        if (j < s) red[j] += red[j + s];
        __syncthreads();
    }
    if (j == 0) out[g] = fminf(fmaxf(red[0] + pb2[0], 0.f), 50.f);
}

struct Params {
    const int *x, *ei, *ea, *batch;
    const float *atom_emb, *vn_emb, *bond_emb, *conv_eps, *conv_W1, *conv_b1;
    const float *cbn_g, *cbn_b, *cbn_m, *cbn_v, *conv_W2, *conv_b2;
    const float *vn1_W, *vn1_b, *vn1_g, *vn1_be, *vn1_m, *vn1_v;
    const float *vn2_W, *vn2_b, *vn2_g, *vn2_be, *vn2_m, *vn2_v;
    const float *pW1, *pb1, *pW2, *pb2;
};
static Params unpack(void* const* d_in) {
    Params p;
    p.x = (const int*)d_in[0]; p.ei = (const int*)d_in[1]; p.ea = (const int*)d_in[2];
    p.batch = (const int*)d_in[3];
    p.atom_emb = (const float*)d_in[4]; p.vn_emb = (const float*)d_in[5];
    p.bond_emb = (const float*)d_in[6]; p.conv_eps = (const float*)d_in[7];
    p.conv_W1 = (const float*)d_in[8]; p.conv_b1 = (const float*)d_in[9];
    p.cbn_g = (const float*)d_in[10]; p.cbn_b = (const float*)d_in[11];
    p.cbn_m = (const float*)d_in[12]; p.cbn_v = (const float*)d_in[13];
    p.conv_W2 = (const float*)d_in[14]; p.conv_b2 = (const float*)d_in[15];
    p.vn1_W = (const float*)d_in[16]; p.vn1_b = (const float*)d_in[17];
    p.vn1_g = (const float*)d_in[18]; p.vn1_be = (const float*)d_in[19];
    p.vn1_m = (const float*)d_in[20]; p.vn1_v = (const float*)d_in[21];
    p.vn2_W = (const float*)d_in[22]; p.vn2_b = (const float*)d_in[23];
    p.vn2_g = (const float*)d_in[24]; p.vn2_be = (const float*)d_in[25];
    p.vn2_m = (const float*)d_in[26]; p.vn2_v = (const float*)d_in[27];
    p.pW1 = (const float*)d_in[28]; p.pb1 = (const float*)d_in[29];
    p.pW2 = (const float*)d_in[30]; p.pb2 = (const float*)d_in[31];
    return p;
}

// ============ primary pipeline: f32 state + fp16 edge snapshot + bucketed agg ============
static void run_main(const Params& P, void* d_out, char* base, int NB, int C,
                     hipStream_t stream) {
    const int NBS = NN / NB;
    const int shift = 31 - __builtin_clz(NBS);   // log2(NBS)
    float*  h      = (float*)base;                                   // NN*HH f32
    ushort* hh     = (ushort*)(base + (size_t)NN * HH * 4);          // NN*HH fp16
    float*  aggc   = (float*)(base + (size_t)NN * HH * 6);           // NBS*HH f32
    float*  zc     = aggc + (size_t)NBS * HH;                        // C*2H f32
    float*  vn     = zc + (size_t)C * 2 * HH;                        // G*H
    float*  vnW    = vn + (size_t)GG * HH;                           // G*2H
    float*  pooled = vnW + (size_t)GG * 2 * HH;                      // G*2H
    float*  out    = (float*)d_out;

    k_atom<false><<<NN * 32 / 256, 256, 0, stream>>>(P.x, P.atom_emb, (void*)h);
    k_init_vn<<<GG * HH / 4 / 256, 256, 0, stream>>>(P.vn_emb, vn);

    for (int i = 0; i < 4; ++i) {
        k_addvn_snap<<<NN * 32 / 256, 256, 0, stream>>>(h, hh, vn, P.batch);

        for (int b = 0; b < NB; ++b) {
            k_zero<<<NBS * HH / 4 / 256, 256, 0, stream>>>(aggc);
            k_edge_b<<<EE * 32 / 256, 256, 0, stream>>>(
                hh, P.ei, P.ea, P.bond_emb + (size_t)i * FBc * VBc * HH,
                aggc, b, shift);
            for (int s = 0; s < NBS; s += C) {
                int r0 = b * NBS + s;
                dim3 g1(C / 64, 2 * HH / 64);
                gemm_k<false, A_Z, E_BNRELU, false><<<g1, 256, 0, stream>>>(
                    h + (size_t)r0 * HH, aggc + (size_t)s * HH,
                    P.conv_W1 + (size_t)i * HH * 2 * HH,
                    P.conv_b1 + i * 2 * HH, P.cbn_g + i * 2 * HH, P.cbn_b + i * 2 * HH,
                    P.cbn_m + i * 2 * HH, P.cbn_v + i * 2 * HH,
                    nullptr, nullptr, P.conv_eps + i, zc, HH, 2 * HH);
                dim3 g2(C / 64, HH / 64);
                gemm_k<false, A_PLAIN, E_BIAS, false><<<g2, 256, 0, stream>>>(
                    zc, nullptr, P.conv_W2 + (size_t)i * 2 * HH * HH,
                    P.conv_b2 + i * HH, nullptr, nullptr, nullptr, nullptr,
                    nullptr, nullptr, nullptr, h + (size_t)r0 * HH, 2 * HH, HH);
            }
        }

        // GEMM3a: vnW = vn @ vn1_W[:128] + vn1_b   [G,256]
        {
            dim3 g3(GG / 64, 2 * HH / 64);
            gemm_k<false, A_PLAIN, E_BIAS, false><<<g3, 256, 0, stream>>>(
                vn, nullptr, P.vn1_W + (size_t)i * 2 * HH * 2 * HH,
                P.vn1_b + i * 2 * HH, nullptr, nullptr, nullptr, nullptr,
                nullptr, nullptr, nullptr, vnW, HH, 2 * HH);
        }
        k_zero<<<GG * 2 * HH / 4 / 256, 256, 0, stream>>>(pooled);
        // GEMM3b: pooled[batch[r]] += relu(bn(h @ vn1_W[128:] + vnW[batch[r]]))
        {
            dim3 g3b(NN / 64, 2 * HH / 64);
            gemm_k<false, A_PLAIN, E_POOL, false><<<g3b, 256, 0, stream>>>(
                h, nullptr,
                P.vn1_W + (size_t)i * 2 * HH * 2 * HH + (size_t)HH * 2 * HH,
                nullptr, P.vn1_g + i * 2 * HH, P.vn1_be + i * 2 * HH,
                P.vn1_m + i * 2 * HH, P.vn1_v + i * 2 * HH,
                vnW, P.batch, nullptr, pooled, HH, 2 * HH);
        }
        // GEMM4: vn = relu(bn(pooled @ vn2_W + vn2_b))   [G,128]
        {
            dim3 g4(GG / 64, HH / 64);
            gemm_k<false, A_PLAIN, E_BNRELU, false><<<g4, 256, 0, stream>>>(
                pooled, nullptr, P.vn2_W + (size_t)i * 2 * HH * HH,
                P.vn2_b + i * HH, P.vn2_g + i * HH, P.vn2_be + i * HH,
                P.vn2_m + i * HH, P.vn2_v + i * HH,
                nullptr, nullptr, nullptr, vn, 2 * HH, HH);
        }
    }
    k_final<<<GG, 128, 0, stream>>>(vn, P.pW1, P.pb1, P.pW2, P.pb2, out);
}

// ============ fallback pipeline: bf16 h, full-N agg (last resort, small ws) ============
static void run_fallback(const Params& P, void* d_out, char* base, size_t ws_size,
                         hipStream_t stream) {
    void*  h      = (void*)base;                                    // N*H bf16
    float* agg    = (float*)(base + (size_t)NN * HH * 2);           // N*H f32
    float* vn     = agg + (size_t)NN * HH;
    float* vnW    = vn + (size_t)GG * HH;
    float* pooled = vnW + (size_t)GG * 2 * HH;
    float* zc     = pooled + (size_t)GG * 2 * HH;
    size_t fixed_bytes = (size_t)NN * HH * 2 + (size_t)NN * HH * 4
                       + (size_t)GG * HH * 4 + 2 * (size_t)GG * 2 * HH * 4;
    size_t rem = ws_size > fixed_bytes ? ws_size - fixed_bytes : 0;
    int C = 65536;
    while (C > 64 && (size_t)C * 2 * HH * 4 > rem) C >>= 1;
    float* out = (float*)d_out;

    k_atom<true><<<NN * 32 / 256, 256, 0, stream>>>(P.x, P.atom_emb, h);
    k_init_vn<<<GG * HH / 4 / 256, 256, 0, stream>>>(P.vn_emb, vn);
    for (int i = 0; i < 4; ++i) {
        k_addvn<true><<<NN * 32 / 256, 256, 0, stream>>>(h, vn, P.batch);
        k_zero<<<NN * HH / 4 / 256, 256, 0, stream>>>(agg);
        k_edge<true><<<EE * 32 / 256, 256, 0, stream>>>(
            h, P.ei, P.ea, P.bond_emb + (size_t)i * FBc * VBc * HH, agg);
        for (int c0 = 0; c0 < NN; c0 += C) {
            int rows = (NN - c0) < C ? (NN - c0) : C;
            dim3 g1(rows / 64, 2 * HH / 64);
            gemm_k<true, A_Z, E_BNRELU, false><<<g1, 256, 0, stream>>>(
                (const char*)h + (size_t)c0 * HH * 2, agg + (size_t)c0 * HH,
                P.conv_W1 + (size_t)i * HH * 2 * HH,
                P.conv_b1 + i * 2 * HH, P.cbn_g + i * 2 * HH, P.cbn_b + i * 2 * HH,
                P.cbn_m + i * 2 * HH, P.cbn_v + i * 2 * HH,
                nullptr, nullptr, P.conv_eps + i, zc, HH, 2 * HH);
            dim3 g2(rows / 64, HH / 64);
            gemm_k<false, A_PLAIN, E_BIAS, true><<<g2, 256, 0, stream>>>(
                zc, nullptr, P.conv_W2 + (size_t)i * 2 * HH * HH,
                P.conv_b2 + i * HH, nullptr, nullptr, nullptr, nullptr,
                nullptr, nullptr, nullptr, (char*)h + (size_t)c0 * HH * 2, 2 * HH, HH);
        }
        {
            dim3 g3(GG / 64, 2 * HH / 64);
            gemm_k<false, A_PLAIN, E_BIAS, false><<<g3, 256, 0, stream>>>(
                vn, nullptr, P.vn1_W + (size_t)i * 2 * HH * 2 * HH,
                P.vn1_b + i * 2 * HH, nullptr, nullptr, nullptr, nullptr,
                nullptr, nullptr, nullptr, vnW, HH, 2 * HH);
        }
        k_zero<<<GG * 2 * HH / 4 / 256, 256, 0, stream>>>(pooled);
        {
            dim3 g3b(NN / 64, 2 * HH / 64);
            gemm_k<true, A_PLAIN, E_POOL, false><<<g3b, 256, 0, stream>>>(
                h, nullptr,
                P.vn1_W + (size_t)i * 2 * HH * 2 * HH + (size_t)HH * 2 * HH,
                nullptr, P.vn1_g + i * 2 * HH, P.vn1_be + i * 2 * HH,
                P.vn1_m + i * 2 * HH, P.vn1_v + i * 2 * HH,
                vnW, P.batch, nullptr, pooled, HH, 2 * HH);
        }
        {
            dim3 g4(GG / 64, HH / 64);
            gemm_k<false, A_PLAIN, E_BNRELU, false><<<g4, 256, 0, stream>>>(
                pooled, nullptr, P.vn2_W + (size_t)i * 2 * HH * HH,
                P.vn2_b + i * HH, P.vn2_g + i * HH, P.vn2_be + i * HH,
                P.vn2_m + i * HH, P.vn2_v + i * HH,
                nullptr, nullptr, nullptr, vn, 2 * HH, HH);
        }
    }
    k_final<<<GG, 128, 0, stream>>>(vn, P.pW1, P.pb1, P.pW2, P.pb2, out);
}

static size_t need_main(int NB, int C) {
    size_t NBS = NN / NB;
    return (size_t)NN * HH * 6 + NBS * HH * 4 + (size_t)C * 2 * HH * 4
         + (size_t)GG * HH * 4 + 2 * (size_t)GG * 2 * HH * 4;
}

extern "C" void kernel_launch(void* const* d_in, const int* in_sizes, int n_in,
                              void* d_out, int out_size, void* d_ws, size_t ws_size,
                              hipStream_t stream) {
    Params P = unpack(d_in);
    static const int cfg[4][2] = {{8, 16384}, {16, 8192}, {32, 4096}, {64, 2048}};
    for (int k = 0; k < 4; ++k) {
        if (need_main(cfg[k][0], cfg[k][1]) <= ws_size) {
            run_main(P, d_out, (char*)d_ws, cfg[k][0], cfg[k][1], stream);
            return;
        }
    }
    run_fallback(P, d_out, (char*)d_ws, ws_size, stream);
}

// Round 6
// 5593.385 us; speedup vs baseline: 2.6706x; 2.6706x over previous
//
#include <hip/hip_runtime.h>
#include <hip/hip_fp16.h>

#define NN 262144
#define EE 1048576
#define GG 8192
#define HH 128
#define FAc 9
#define FBc 3
#define VAc 64
#define VBc 8

// ---- fp16 <-> f32 helpers ----
__device__ __forceinline__ float h2f(ushort u) {
    __half h; *(ushort*)&h = u; return __half2float(h);
}
__device__ __forceinline__ ushort f2h(float f) {
    __half h = __float2half_rn(f); return *(ushort*)&h;
}

// dtype codes for GEMM operands.
// NOTE: all fp16 buffers store value/16 (exact pow2 scale) to avoid fp16
// overflow from layer-wise activation growth; load multiplies back by 16.
#define DT_F32 0
#define DT_F16 1

template <int DT>
__device__ __forceinline__ float4 load4d(const void* p, size_t off) {
    if (DT == DT_F16) {
        ushort4 u = *(const ushort4*)((const ushort*)p + off);
        return make_float4(16.f * h2f(u.x), 16.f * h2f(u.y),
                           16.f * h2f(u.z), 16.f * h2f(u.w));
    } else {
        return *(const float4*)((const float*)p + off);
    }
}
template <int DT>
__device__ __forceinline__ void store4d(void* p, size_t off, float4 v) {
    if (DT == DT_F16) {
        ushort4 o;
        o.x = f2h(v.x * 0.0625f); o.y = f2h(v.y * 0.0625f);
        o.z = f2h(v.z * 0.0625f); o.w = f2h(v.w * 0.0625f);
        *(ushort4*)((ushort*)p + off) = o;
    } else {
        *(float4*)((float*)p + off) = v;
    }
}

// ---------------- zero fill (graph-capture-safe memset) ----------------
__global__ void k_zero(float* __restrict__ p) {
    size_t i = (size_t)(blockIdx.x * 256 + threadIdx.x) * 4;
    *(float4*)(p + i) = make_float4(0.f, 0.f, 0.f, 0.f);
}

// ---------------- atom encoder ----------------
__global__ void k_atom(const int* __restrict__ x, const float* __restrict__ emb,
                       float* __restrict__ h) {
    int t = blockIdx.x * 256 + threadIdx.x;
    int n = t >> 5, c = (t & 31) << 2;
    if (n >= NN) return;
    float4 a = make_float4(0.f, 0.f, 0.f, 0.f);
#pragma unroll
    for (int f = 0; f < FAc; ++f) {
        int v = x[n * FAc + f];
        float4 e = *(const float4*)(emb + ((size_t)(f * VAc + v)) * HH + c);
        a.x += e.x; a.y += e.y; a.z += e.z; a.w += e.w;
    }
    *(float4*)(h + (size_t)n * HH + c) = a;
}

// ---------------- vn init ----------------
__global__ void k_init_vn(const float* __restrict__ vn_emb, float* __restrict__ vn) {
    int t = blockIdx.x * 256 + threadIdx.x;
    int g = t >> 5, c = (t & 31) << 2;
    *(float4*)(vn + (size_t)g * HH + c) = *(const float4*)(vn_emb + c);
}

// ---------------- h += vn[batch] ----------------
__global__ void k_addvn(float* __restrict__ h, const float* __restrict__ vn,
                        const int* __restrict__ batch) {
    int t = blockIdx.x * 256 + threadIdx.x;
    int n = t >> 5, c = (t & 31) << 2;
    size_t off = (size_t)n * HH + c;
    float4 hv = *(const float4*)(h + off);
    float4 vv = *(const float4*)(vn + (size_t)batch[n] * HH + c);
    hv.x += vv.x; hv.y += vv.y; hv.z += vv.z; hv.w += vv.w;
    *(float4*)(h + off) = hv;
}

// ================= CSR build (once per launch) =================
__global__ void k_hist(const int* __restrict__ ei, int* __restrict__ deg) {
    int e = blockIdx.x * 256 + threadIdx.x;
    atomicAdd(&deg[ei[EE + e]], 1);
}

// block-level scan: 256 blocks x 256 threads x 4 elems = N
__global__ void k_scan1(const int* __restrict__ deg, int* __restrict__ rowptr,
                        int* __restrict__ sums) {
    __shared__ int s[256];
    int base = blockIdx.x * 1024 + threadIdx.x * 4;
    int4 d = *(const int4*)(deg + base);
    int t = d.x + d.y + d.z + d.w;
    s[threadIdx.x] = t;
    __syncthreads();
    for (int off = 1; off < 256; off <<= 1) {
        int v = (threadIdx.x >= off) ? s[threadIdx.x - off] : 0;
        __syncthreads();
        s[threadIdx.x] += v;
        __syncthreads();
    }
    int excl = s[threadIdx.x] - t;
    int4 o; o.x = excl; o.y = excl + d.x; o.z = o.y + d.y; o.w = o.z + d.z;
    *(int4*)(rowptr + base) = o;
    if (threadIdx.x == 255) sums[blockIdx.x] = s[255];
}

__global__ void k_scan2(int* __restrict__ sums) {
    __shared__ int s[256];
    int t = sums[threadIdx.x];
    s[threadIdx.x] = t;
    __syncthreads();
    for (int off = 1; off < 256; off <<= 1) {
        int v = (threadIdx.x >= off) ? s[threadIdx.x - off] : 0;
        __syncthreads();
        s[threadIdx.x] += v;
        __syncthreads();
    }
    sums[threadIdx.x] = s[threadIdx.x] - t;   // exclusive
}

__global__ void k_scan3(int* __restrict__ rowptr, const int* __restrict__ sums,
                        int* __restrict__ fill) {
    int base = blockIdx.x * 1024 + threadIdx.x * 4;
    int add = sums[blockIdx.x];
    int4 r = *(const int4*)(rowptr + base);
    r.x += add; r.y += add; r.z += add; r.w += add;
    *(int4*)(rowptr + base) = r;
    *(int4*)(fill + base) = r;
    if (blockIdx.x == 0 && threadIdx.x == 0) rowptr[NN] = EE;
}

__global__ void k_scatter(const int* __restrict__ ei, const int* __restrict__ ea,
                          int* __restrict__ fill, unsigned* __restrict__ packed) {
    int e = blockIdx.x * 256 + threadIdx.x;
    int dst = ei[EE + e];
    int pos = atomicAdd(&fill[dst], 1);
    unsigned cb = (unsigned)(ea[e * 3 + 0] + ea[e * 3 + 1] * 8 + ea[e * 3 + 2] * 64);
    packed[pos] = (unsigned)ei[e] | (cb << 18);
}

// per-layer bond-combo table: ctab[cb][c] = sum of 3 bond embeddings
__global__ void k_ctab(const float* __restrict__ bemb, float* __restrict__ ctab) {
    int t = blockIdx.x * 256 + threadIdx.x;   // 16384
    int cb = t >> 5, c = (t & 31) << 2;
    int a0 = cb & 7, a1 = (cb >> 3) & 7, a2 = cb >> 6;
    float4 b0 = *(const float4*)(bemb + (size_t)(0 * VBc + a0) * HH + c);
    float4 b1 = *(const float4*)(bemb + (size_t)(1 * VBc + a1) * HH + c);
    float4 b2 = *(const float4*)(bemb + (size_t)(2 * VBc + a2) * HH + c);
    float4 o = make_float4(b0.x + b1.x + b2.x, b0.y + b1.y + b2.y,
                           b0.z + b1.z + b2.z, b0.w + b1.w + b2.w);
    *(float4*)(ctab + (size_t)cb * HH + c) = o;
}

// CSR aggregation: one wave per node, no atomics. agg[n] = (1/16)*sum relu(h[src]+ctab[cb]) fp16
__global__ void k_agg(const float* __restrict__ h, const int* __restrict__ rowptr,
                      const unsigned* __restrict__ packed, const float* __restrict__ ctab,
                      ushort* __restrict__ agg) {
    int n = blockIdx.x * 4 + (threadIdx.x >> 6);
    int lane = threadIdx.x & 63;
    int beg = rowptr[n], end = rowptr[n + 1];
    float a0 = 0.f, a1 = 0.f;
    for (int i = beg; i < end; ++i) {
        unsigned p = packed[i];
        int src = p & 0x3FFFF;
        int cb = p >> 18;
        float2 hv = *(const float2*)(h + (size_t)src * HH + lane * 2);
        float2 ct = *(const float2*)(ctab + (size_t)cb * HH + lane * 2);
        a0 += fmaxf(hv.x + ct.x, 0.f);
        a1 += fmaxf(hv.y + ct.y, 0.f);
    }
    ushort2 o; o.x = f2h(a0 * 0.0625f); o.y = f2h(a1 * 0.0625f);
    *(ushort2*)(agg + (size_t)n * HH + lane * 2) = o;
}

// ---------------- tiled GEMM, 64x64 tile, BK=32, fused epilogues ----------------
enum { A_PLAIN = 0, A_Z = 1 };
enum { E_BIAS = 0, E_BNRELU = 1, E_POOL = 2 };

template <int ADT, int A2DT, int AMODE, int EMODE, int ODT, bool SWZ>
__global__ void __launch_bounds__(256)
gemm_k(const void* __restrict__ Av, const void* __restrict__ A2,
       const float* __restrict__ B,
       const float* __restrict__ bias,
       const float* __restrict__ g_, const float* __restrict__ b_,
       const float* __restrict__ m_, const float* __restrict__ v_,
       const float* __restrict__ addrow, const int* __restrict__ batch,
       const float* __restrict__ eps_ptr,
       void* __restrict__ outv, int K, int Nc) {
    __shared__ float As[64][33];
    __shared__ float Bs[32][64];
    const int tid = threadIdx.x;
    int bx = blockIdx.x;
    if (SWZ) bx = (bx & 7) * (gridDim.x >> 3) + (bx >> 3);   // XCD-chunked rows
    const int row0 = bx * 64;
    const int col0 = blockIdx.y * 64;
    float eps1 = 0.f;
    if (AMODE == A_Z) eps1 = 1.f + eps_ptr[0];
    float acc[4][4] = {};
    const int tx = tid & 15, ty = tid >> 4;

    for (int k0 = 0; k0 < K; k0 += 32) {
#pragma unroll
        for (int p = 0; p < 2; ++p) {
            int idx = p * 256 + tid;
            {   // A tile: 64 rows x 32 cols
                int r = idx >> 3, c = (idx & 7) << 2;
                size_t aoff = (size_t)(row0 + r) * K + k0 + c;
                float4 va = load4d<ADT>(Av, aoff);
                if (AMODE == A_Z) {
                    float4 vg = load4d<A2DT>(A2, aoff);
                    va.x = eps1 * va.x + vg.x; va.y = eps1 * va.y + vg.y;
                    va.z = eps1 * va.z + vg.z; va.w = eps1 * va.w + vg.w;
                }
                As[r][c + 0] = va.x; As[r][c + 1] = va.y;
                As[r][c + 2] = va.z; As[r][c + 3] = va.w;
            }
            {   // B tile: 32 rows x 64 cols (weights f32)
                int kr = idx >> 4, cc = (idx & 15) << 2;
                *(float4*)&Bs[kr][cc] =
                    *(const float4*)(B + (size_t)(k0 + kr) * Nc + col0 + cc);
            }
        }
        __syncthreads();
#pragma unroll
        for (int k = 0; k < 32; ++k) {
            float4 bv = *(const float4*)&Bs[k][tx << 2];
            float a0 = As[ty * 4 + 0][k];
            float a1 = As[ty * 4 + 1][k];
            float a2 = As[ty * 4 + 2][k];
            float a3 = As[ty * 4 + 3][k];
            acc[0][0] += a0 * bv.x; acc[0][1] += a0 * bv.y; acc[0][2] += a0 * bv.z; acc[0][3] += a0 * bv.w;
            acc[1][0] += a1 * bv.x; acc[1][1] += a1 * bv.y; acc[1][2] += a1 * bv.z; acc[1][3] += a1 * bv.w;
            acc[2][0] += a2 * bv.x; acc[2][1] += a2 * bv.y; acc[2][2] += a2 * bv.z; acc[2][3] += a2 * bv.w;
            acc[3][0] += a3 * bv.x; acc[3][1] += a3 * bv.y; acc[3][2] += a3 * bv.z; acc[3][3] += a3 * bv.w;
        }
        __syncthreads();
    }

    if (EMODE == E_POOL) {
        // run-length merged atomic pooling over consecutive (sorted-batch) rows
        int prevg = -1;
        float accv[4] = {0.f, 0.f, 0.f, 0.f};
#pragma unroll
        for (int j = 0; j < 4; ++j) {
            int gr = row0 + ty * 4 + j;
            int gg = batch[gr];
            if (gg != prevg && prevg != -1) {
#pragma unroll
                for (int l = 0; l < 4; ++l) {
                    atomicAdd((float*)outv + (size_t)prevg * Nc + col0 + (tx << 2) + l, accv[l]);
                    accv[l] = 0.f;
                }
            }
#pragma unroll
            for (int l = 0; l < 4; ++l) {
                int gc = col0 + (tx << 2) + l;
                float y = acc[j][l] + addrow[(size_t)gg * Nc + gc];
                float s = g_[gc] * rsqrtf(v_[gc] + 1e-5f);
                y = (y - m_[gc]) * s + b_[gc];
                accv[l] += fmaxf(y, 0.f);
            }
            prevg = gg;
        }
#pragma unroll
        for (int l = 0; l < 4; ++l)
            atomicAdd((float*)outv + (size_t)prevg * Nc + col0 + (tx << 2) + l, accv[l]);
    } else {
#pragma unroll
        for (int j = 0; j < 4; ++j) {
            int gr = row0 + ty * 4 + j;
            float vals[4];
#pragma unroll
            for (int l = 0; l < 4; ++l) {
                int gc = col0 + (tx << 2) + l;
                float val = acc[j][l];
                if (EMODE == E_BIAS) {
                    vals[l] = val + bias[gc];
                } else {  // E_BNRELU
                    float y = val + bias[gc];
                    float s = g_[gc] * rsqrtf(v_[gc] + 1e-5f);
                    y = (y - m_[gc]) * s + b_[gc];
                    vals[l] = fmaxf(y, 0.f);
                }
            }
            store4d<ODT>(outv, (size_t)gr * Nc + col0 + (tx << 2),
                         make_float4(vals[0], vals[1], vals[2], vals[3]));
        }
    }
}

// ---------------- final head ----------------
__global__ void k_final(const float* __restrict__ vn, const float* __restrict__ pW1,
                        const float* __restrict__ pb1, const float* __restrict__ pW2,
                        const float* __restrict__ pb2, float* __restrict__ out) {
    int g = blockIdx.x;
    int j = threadIdx.x;  // 128 threads
    __shared__ float vrow[HH];
    __shared__ float red[HH];
    vrow[j] = vn[(size_t)g * HH + j];
    __syncthreads();
    float acc = pb1[j];
    for (int k = 0; k < HH; ++k) acc = fmaf(vrow[k], pW1[k * HH + j], acc);
    red[j] = fmaxf(acc, 0.f) * pW2[j];
    __syncthreads();
    for (int s = 64; s > 0; s >>= 1) {
        if (j < s) red[j] += red[j + s];
        __syncthreads();
    }
    if (j == 0) out[g] = fminf(fmaxf(red[0] + pb2[0], 0.f), 50.f);
}

extern "C" void kernel_launch(void* const* d_in, const int* in_sizes, int n_in,
                              void* d_out, int out_size, void* d_ws, size_t ws_size,
                              hipStream_t stream) {
    const int*   x        = (const int*)  d_in[0];
    const int*   ei       = (const int*)  d_in[1];
    const int*   ea       = (const int*)  d_in[2];
    const int*   batch    = (const int*)  d_in[3];
    const float* atom_emb = (const float*)d_in[4];
    const float* vn_emb   = (const float*)d_in[5];
    const float* bond_emb = (const float*)d_in[6];
    const float* conv_eps = (const float*)d_in[7];
    const float* conv_W1  = (const float*)d_in[8];
    const float* conv_b1  = (const float*)d_in[9];
    const float* cbn_g    = (const float*)d_in[10];
    const float* cbn_b    = (const float*)d_in[11];
    const float* cbn_m    = (const float*)d_in[12];
    const float* cbn_v    = (const float*)d_in[13];
    const float* conv_W2  = (const float*)d_in[14];
    const float* conv_b2  = (const float*)d_in[15];
    const float* vn1_W    = (const float*)d_in[16];
    const float* vn1_b    = (const float*)d_in[17];
    const float* vn1_g    = (const float*)d_in[18];
    const float* vn1_be   = (const float*)d_in[19];
    const float* vn1_m    = (const float*)d_in[20];
    const float* vn1_v    = (const float*)d_in[21];
    const float* vn2_W    = (const float*)d_in[22];
    const float* vn2_b    = (const float*)d_in[23];
    const float* vn2_g    = (const float*)d_in[24];
    const float* vn2_be   = (const float*)d_in[25];
    const float* vn2_m    = (const float*)d_in[26];
    const float* vn2_v    = (const float*)d_in[27];
    const float* pW1      = (const float*)d_in[28];
    const float* pb1      = (const float*)d_in[29];
    const float* pW2      = (const float*)d_in[30];
    const float* pb2      = (const float*)d_in[31];

    // ---- workspace layout (all 16B aligned), ~245.6 MB total ----
    const int C = 32768;                                     // conv chunk rows
    char* base = (char*)d_ws;
    float*    h      = (float*)base;                                  // NN*HH f32   134.2 MB
    ushort*   agg    = (ushort*)(base + (size_t)NN * HH * 4);         // NN*HH fp16   67.1 MB
    ushort*   zc     = agg + (size_t)NN * HH;                         // C*2H fp16    16.8 MB
    unsigned* packed = (unsigned*)(zc + (size_t)C * 2 * HH);          // EE u32        4.2 MB
    int*      rowptr = (int*)(packed + EE);                           // NN+4 int      1.0 MB
    int*      fill   = rowptr + NN + 4;                               // NN int        1.0 MB
    float*    ctab   = (float*)(fill + NN);                           // 512*HH f32    0.3 MB
    int*      sums   = (int*)(ctab + 512 * HH);                       // 256 int
    float*    vn     = (float*)(sums + 256);                          // G*H           4.2 MB
    float*    vnW    = vn + (size_t)GG * HH;                          // G*2H          8.4 MB
    float*    pooled = vnW + (size_t)GG * 2 * HH;                     // G*2H          8.4 MB
    float*    out    = (float*)d_out;

    // ---- CSR build (graph is static across layers) ----
    k_zero<<<256, 256, 0, stream>>>((float*)fill);                    // fill used as deg
    k_hist<<<EE / 256, 256, 0, stream>>>(ei, fill);
    k_scan1<<<256, 256, 0, stream>>>(fill, rowptr, sums);
    k_scan2<<<1, 256, 0, stream>>>(sums);
    k_scan3<<<256, 256, 0, stream>>>(rowptr, sums, fill);
    k_scatter<<<EE / 256, 256, 0, stream>>>(ei, ea, fill, packed);

    k_atom<<<NN * 32 / 256, 256, 0, stream>>>(x, atom_emb, h);
    k_init_vn<<<GG * HH / 4 / 256, 256, 0, stream>>>(vn_emb, vn);

    for (int i = 0; i < 4; ++i) {
        k_addvn<<<NN * 32 / 256, 256, 0, stream>>>(h, vn, batch);
        k_ctab<<<64, 256, 0, stream>>>(bond_emb + (size_t)i * FBc * VBc * HH, ctab);
        k_agg<<<NN / 4, 256, 0, stream>>>(h, rowptr, packed, ctab, agg);

        // conv MLP chunked: z = relu(bn(((1+eps)h+agg)@W1+b1)) (fp16/16); h = z@W2+b2 (f32, in place)
        for (int c0 = 0; c0 < NN; c0 += C) {
            dim3 g1(C / 64, 2 * HH / 64);
            gemm_k<DT_F32, DT_F16, A_Z, E_BNRELU, DT_F16, false><<<g1, 256, 0, stream>>>(
                h + (size_t)c0 * HH, agg + (size_t)c0 * HH,
                conv_W1 + (size_t)i * HH * 2 * HH,
                conv_b1 + i * 2 * HH, cbn_g + i * 2 * HH, cbn_b + i * 2 * HH,
                cbn_m + i * 2 * HH, cbn_v + i * 2 * HH,
                nullptr, nullptr, conv_eps + i, zc, HH, 2 * HH);
            dim3 g2(C / 64, HH / 64);
            gemm_k<DT_F16, DT_F32, A_PLAIN, E_BIAS, DT_F32, false><<<g2, 256, 0, stream>>>(
                zc, nullptr, conv_W2 + (size_t)i * 2 * HH * HH,
                conv_b2 + i * HH, nullptr, nullptr, nullptr, nullptr,
                nullptr, nullptr, nullptr, h + (size_t)c0 * HH, 2 * HH, HH);
        }

        // GEMM3a: vnW = vn @ vn1_W[:128] + vn1_b   [G,256]
        {
            dim3 g3(GG / 64, 2 * HH / 64);
            gemm_k<DT_F32, DT_F32, A_PLAIN, E_BIAS, DT_F32, false><<<g3, 256, 0, stream>>>(
                vn, nullptr, vn1_W + (size_t)i * 2 * HH * 2 * HH,
                vn1_b + i * 2 * HH, nullptr, nullptr, nullptr, nullptr,
                nullptr, nullptr, nullptr, vnW, HH, 2 * HH);
        }
        k_zero<<<GG * 2 * HH / 4 / 256, 256, 0, stream>>>(pooled);
        // GEMM3b: pooled[batch[r]] += relu(bn(h @ vn1_W[128:] + vnW[batch[r]]))  (swizzled+merged)
        {
            dim3 g3b(NN / 64, 2 * HH / 64);
            gemm_k<DT_F32, DT_F32, A_PLAIN, E_POOL, DT_F32, true><<<g3b, 256, 0, stream>>>(
                h, nullptr,
                vn1_W + (size_t)i * 2 * HH * 2 * HH + (size_t)HH * 2 * HH,
                nullptr, vn1_g + i * 2 * HH, vn1_be + i * 2 * HH,
                vn1_m + i * 2 * HH, vn1_v + i * 2 * HH,
                vnW, batch, nullptr, pooled, HH, 2 * HH);
        }
        // GEMM4: vn = relu(bn(pooled @ vn2_W + vn2_b))   [G,128]
        {
            dim3 g4(GG / 64, HH / 64);
            gemm_k<DT_F32, DT_F32, A_PLAIN, E_BNRELU, DT_F32, false><<<g4, 256, 0, stream>>>(
                pooled, nullptr, vn2_W + (size_t)i * 2 * HH * HH,
                vn2_b + i * HH, vn2_g + i * HH, vn2_be + i * HH,
                vn2_m + i * HH, vn2_v + i * HH,
                nullptr, nullptr, nullptr, vn, 2 * HH, HH);
        }
    }
    k_final<<<GG, 128, 0, stream>>>(vn, pW1, pb1, pW2, pb2, out);
}

// Round 7
// 3311.329 us; speedup vs baseline: 4.5110x; 1.6892x over previous
//
#include <hip/hip_runtime.h>
#include <hip/hip_fp16.h>

#define NN 262144
#define EE 1048576
#define GG 8192
#define HH 128
#define FAc 9
#define FBc 3
#define VAc 64
#define VBc 8
#define CCH 32768   // conv chunk rows

typedef _Float16 f16;
typedef _Float16 f16x8 __attribute__((ext_vector_type(8)));
typedef float f32x4 __attribute__((ext_vector_type(4)));

// ---- fp16 <-> f32 helpers ----
__device__ __forceinline__ float h2f(ushort u) {
    __half h; *(ushort*)&h = u; return __half2float(h);
}
__device__ __forceinline__ ushort f2h(float f) {
    __half h = __float2half_rn(f); return *(ushort*)&h;
}

#define DT_F32 0
#define DT_F16 1
template <int DT>
__device__ __forceinline__ float4 load4d(const void* p, size_t off) {
    if (DT == DT_F16) {
        ushort4 u = *(const ushort4*)((const ushort*)p + off);
        return make_float4(16.f * h2f(u.x), 16.f * h2f(u.y),
                           16.f * h2f(u.z), 16.f * h2f(u.w));
    } else {
        return *(const float4*)((const float*)p + off);
    }
}
template <int DT>
__device__ __forceinline__ void store4d(void* p, size_t off, float4 v) {
    if (DT == DT_F16) {
        ushort4 o;
        o.x = f2h(v.x * 0.0625f); o.y = f2h(v.y * 0.0625f);
        o.z = f2h(v.z * 0.0625f); o.w = f2h(v.w * 0.0625f);
        *(ushort4*)((ushort*)p + off) = o;
    } else {
        *(float4*)((float*)p + off) = v;
    }
}

// ---------------- zero fill ----------------
__global__ void k_zero(float* __restrict__ p) {
    size_t i = (size_t)(blockIdx.x * 256 + threadIdx.x) * 4;
    *(float4*)(p + i) = make_float4(0.f, 0.f, 0.f, 0.f);
}

// ---------------- atom encoder ----------------
__global__ void k_atom(const int* __restrict__ x, const float* __restrict__ emb,
                       float* __restrict__ h) {
    int t = blockIdx.x * 256 + threadIdx.x;
    int n = t >> 5, c = (t & 31) << 2;
    if (n >= NN) return;
    float4 a = make_float4(0.f, 0.f, 0.f, 0.f);
#pragma unroll
    for (int f = 0; f < FAc; ++f) {
        int v = x[n * FAc + f];
        float4 e = *(const float4*)(emb + ((size_t)(f * VAc + v)) * HH + c);
        a.x += e.x; a.y += e.y; a.z += e.z; a.w += e.w;
    }
    *(float4*)(h + (size_t)n * HH + c) = a;
}

// ---------------- vn init ----------------
__global__ void k_init_vn(const float* __restrict__ vn_emb, float* __restrict__ vn) {
    int t = blockIdx.x * 256 + threadIdx.x;
    int g = t >> 5, c = (t & 31) << 2;
    *(float4*)(vn + (size_t)g * HH + c) = *(const float4*)(vn_emb + c);
}

// ================= CSR build =================
__global__ void k_hist(const int* __restrict__ ei, int* __restrict__ deg) {
    int e = blockIdx.x * 256 + threadIdx.x;
    atomicAdd(&deg[ei[EE + e]], 1);
}
__global__ void k_scan1(const int* __restrict__ deg, int* __restrict__ rowptr,
                        int* __restrict__ sums) {
    __shared__ int s[256];
    int base = blockIdx.x * 1024 + threadIdx.x * 4;
    int4 d = *(const int4*)(deg + base);
    int t = d.x + d.y + d.z + d.w;
    s[threadIdx.x] = t;
    __syncthreads();
    for (int off = 1; off < 256; off <<= 1) {
        int v = (threadIdx.x >= off) ? s[threadIdx.x - off] : 0;
        __syncthreads();
        s[threadIdx.x] += v;
        __syncthreads();
    }
    int excl = s[threadIdx.x] - t;
    int4 o; o.x = excl; o.y = excl + d.x; o.z = o.y + d.y; o.w = o.z + d.z;
    *(int4*)(rowptr + base) = o;
    if (threadIdx.x == 255) sums[blockIdx.x] = s[255];
}
__global__ void k_scan2(int* __restrict__ sums) {
    __shared__ int s[256];
    int t = sums[threadIdx.x];
    s[threadIdx.x] = t;
    __syncthreads();
    for (int off = 1; off < 256; off <<= 1) {
        int v = (threadIdx.x >= off) ? s[threadIdx.x - off] : 0;
        __syncthreads();
        s[threadIdx.x] += v;
        __syncthreads();
    }
    sums[threadIdx.x] = s[threadIdx.x] - t;
}
__global__ void k_scan3(int* __restrict__ rowptr, const int* __restrict__ sums,
                        int* __restrict__ fill) {
    int base = blockIdx.x * 1024 + threadIdx.x * 4;
    int add = sums[blockIdx.x];
    int4 r = *(const int4*)(rowptr + base);
    r.x += add; r.y += add; r.z += add; r.w += add;
    *(int4*)(rowptr + base) = r;
    *(int4*)(fill + base) = r;
    if (blockIdx.x == 0 && threadIdx.x == 0) rowptr[NN] = EE;
}
__global__ void k_scatter(const int* __restrict__ ei, const int* __restrict__ ea,
                          int* __restrict__ fill, unsigned* __restrict__ packed) {
    int e = blockIdx.x * 256 + threadIdx.x;
    int dst = ei[EE + e];
    int pos = atomicAdd(&fill[dst], 1);
    unsigned cb = (unsigned)(ea[e * 3 + 0] + ea[e * 3 + 1] * 8 + ea[e * 3 + 2] * 64);
    packed[pos] = (unsigned)ei[e] | (cb << 18);
}

// graph row ranges from sorted batch: gstart[g]..gstart[g+1]
__global__ void k_gstart(const int* __restrict__ batch, int* __restrict__ gstart) {
    int n = blockIdx.x * 256 + threadIdx.x;
    if (n >= NN) return;
    int b0 = batch[n];
    int b1 = (n + 1 < NN) ? batch[n + 1] : GG;
    if (n == 0) gstart[0] = 0;
    for (int g = b0 + 1; g <= b1; ++g) gstart[g] = n + 1;
}

// per-layer bond-combo table
__global__ void k_ctab(const float* __restrict__ bemb, float* __restrict__ ctab) {
    int t = blockIdx.x * 256 + threadIdx.x;
    int cb = t >> 5, c = (t & 31) << 2;
    int a0 = cb & 7, a1 = (cb >> 3) & 7, a2 = cb >> 6;
    float4 b0 = *(const float4*)(bemb + (size_t)(0 * VBc + a0) * HH + c);
    float4 b1 = *(const float4*)(bemb + (size_t)(1 * VBc + a1) * HH + c);
    float4 b2 = *(const float4*)(bemb + (size_t)(2 * VBc + a2) * HH + c);
    float4 o = make_float4(b0.x + b1.x + b2.x, b0.y + b1.y + b2.y,
                           b0.z + b1.z + b2.z, b0.w + b1.w + b2.w);
    *(float4*)(ctab + (size_t)cb * HH + c) = o;
}

// weight transpose: W [K][Nsrc] f32 -> Wt [N][K] fp16, o = c*K + k
__global__ void k_wt(const float* __restrict__ W, ushort* __restrict__ Wt, int lk, int Nsrc) {
    int o = blockIdx.x * 256 + threadIdx.x;
    int K = 1 << lk;
    int c = o >> lk, k = o & (K - 1);
    Wt[o] = f2h(W[(size_t)k * Nsrc + c]);
}

// CSR aggregation (+fused vn add): agg[n] = (1/16) sum relu(h[src]+vn[batch[src]]+ctab)
__global__ void k_agg(const float* __restrict__ h, const float* __restrict__ vn,
                      const int* __restrict__ batch,
                      const int* __restrict__ rowptr, const unsigned* __restrict__ packed,
                      const float* __restrict__ ctab, ushort* __restrict__ agg) {
    int n = blockIdx.x * 4 + (threadIdx.x >> 6);
    int lane = threadIdx.x & 63;
    int beg = rowptr[n], end = rowptr[n + 1];
    float a0 = 0.f, a1 = 0.f;
    for (int i = beg; i < end; ++i) {
        unsigned p = packed[i];
        int src = p & 0x3FFFF;
        int cb = p >> 18;
        float2 hv = *(const float2*)(h + (size_t)src * HH + lane * 2);
        float2 vv = *(const float2*)(vn + (size_t)batch[src] * HH + lane * 2);
        float2 ct = *(const float2*)(ctab + (size_t)cb * HH + lane * 2);
        a0 += fmaxf(hv.x + vv.x + ct.x, 0.f);
        a1 += fmaxf(hv.y + vv.y + ct.y, 0.f);
    }
    ushort2 o; o.x = f2h(a0 * 0.0625f); o.y = f2h(a1 * 0.0625f);
    *(ushort2*)(agg + (size_t)n * HH + lane * 2) = o;
}

// ============== MFMA GEMM: 128x64 tile, BK=32, fp16 in / f32 acc ==============
// MODE 1: A = ((1+eps)(h+vn[batch])+agg)  -> bias+BN+relu -> zc (fp16/16)   K=128 Nc=256
// MODE 2: A = zc (fp16/16 direct)         -> +bias        -> h  (f32)      K=256 Nc=128
// MODE 3: A = h                           -> +vnW[batch]+BN+relu -> t fp16 K=128 Nc=256
template <int MODE>
__global__ void __launch_bounds__(256)
mfma_gemm(const float* __restrict__ hA, const ushort* __restrict__ hU,
          const ushort* __restrict__ Wt, const int* __restrict__ batch,
          const float* __restrict__ vrow, const float* __restrict__ eps_ptr,
          const float* __restrict__ bias,
          const float* __restrict__ g_, const float* __restrict__ b_,
          const float* __restrict__ m_, const float* __restrict__ v_,
          void* __restrict__ outp, int K, int Nc) {
    __shared__ ushort As[128][40];   // pad 40 -> 2-way-max bank aliasing
    __shared__ ushort Bs[64][40];
    const int tid = threadIdx.x;
    const int row0 = blockIdx.x * 128;
    const int col0 = blockIdx.y * 64;
    const int wid = tid >> 6, lane = tid & 63;
    const int lr = lane & 15, lg = lane >> 4;
    const int sr = tid >> 1, sc = (tid & 1) * 16;      // A staging: row, col16-block
    const int bc = tid >> 2, bk = (tid & 3) * 8;       // B staging
    float eps1 = 0.f;
    if (MODE == 1) eps1 = 1.f + eps_ptr[0];
    f32x4 acc[2][4] = {};

    for (int k0 = 0; k0 < K; k0 += 32) {
        // ---- stage A (stored value/16) ----
        if (MODE == 2) {
            const uint4* src = (const uint4*)(hU + (size_t)(row0 + sr) * K + k0 + sc);
            *(uint4*)&As[sr][sc] = src[0];
            *(uint4*)&As[sr][sc + 8] = src[1];
        } else {
            const float* hp = hA + (size_t)(row0 + sr) * K + k0 + sc;
            float4 h0 = *(const float4*)(hp + 0), h1 = *(const float4*)(hp + 4);
            float4 h2 = *(const float4*)(hp + 8), h3 = *(const float4*)(hp + 12);
            float a[16] = {h0.x, h0.y, h0.z, h0.w, h1.x, h1.y, h1.z, h1.w,
                           h2.x, h2.y, h2.z, h2.w, h3.x, h3.y, h3.z, h3.w};
            if (MODE == 1) {
                const float* vp = vrow + (size_t)batch[row0 + sr] * HH + k0 + sc;
                float4 v0 = *(const float4*)(vp + 0), v1 = *(const float4*)(vp + 4);
                float4 v2 = *(const float4*)(vp + 8), v3 = *(const float4*)(vp + 12);
                float vv[16] = {v0.x, v0.y, v0.z, v0.w, v1.x, v1.y, v1.z, v1.w,
                                v2.x, v2.y, v2.z, v2.w, v3.x, v3.y, v3.z, v3.w};
                const ushort* ap = hU + (size_t)(row0 + sr) * K + k0 + sc;
                f16x8 u0 = *(const f16x8*)ap;
                f16x8 u1 = *(const f16x8*)(ap + 8);
#pragma unroll
                for (int j = 0; j < 8; ++j) {
                    a[j]     = eps1 * (a[j] + vv[j]) * 0.0625f + (float)u0[j];
                    a[8 + j] = eps1 * (a[8 + j] + vv[8 + j]) * 0.0625f + (float)u1[j];
                }
            } else {  // MODE 3
#pragma unroll
                for (int j = 0; j < 16; ++j) a[j] *= 0.0625f;
            }
            f16x8 o0, o1;
#pragma unroll
            for (int j = 0; j < 8; ++j) { o0[j] = (f16)a[j]; o1[j] = (f16)a[8 + j]; }
            *(f16x8*)&As[sr][sc] = o0;
            *(f16x8*)&As[sr][sc + 8] = o1;
        }
        // ---- stage B ----
        *(uint4*)&Bs[bc][bk] = *(const uint4*)(Wt + (size_t)(col0 + bc) * K + k0 + bk);
        __syncthreads();
        // ---- MFMA ----
        f16x8 af0 = *(const f16x8*)&As[wid * 32 + lr][lg * 8];
        f16x8 af1 = *(const f16x8*)&As[wid * 32 + 16 + lr][lg * 8];
#pragma unroll
        for (int fc = 0; fc < 4; ++fc) {
            f16x8 bf = *(const f16x8*)&Bs[fc * 16 + lr][lg * 8];
            acc[0][fc] = __builtin_amdgcn_mfma_f32_16x16x32_f16(af0, bf, acc[0][fc], 0, 0, 0);
            acc[1][fc] = __builtin_amdgcn_mfma_f32_16x16x32_f16(af1, bf, acc[1][fc], 0, 0, 0);
        }
        __syncthreads();
    }

    // ---- epilogue (C/D: col=lane&15, row=(lane>>4)*4+reg) ----
#pragma unroll
    for (int fr = 0; fr < 2; ++fr) {
#pragma unroll
        for (int reg = 0; reg < 4; ++reg) {
            int r = row0 + wid * 32 + fr * 16 + lg * 4 + reg;
            const float* ar = nullptr;
            if (MODE == 3) ar = vrow + (size_t)batch[r] * 256;
#pragma unroll
            for (int fc = 0; fc < 4; ++fc) {
                int col = col0 + fc * 16 + lr;
                float val = acc[fr][fc][reg] * 16.f;
                if (MODE == 1) {
                    float y = val + bias[col];
                    y = (y - m_[col]) * (g_[col] * rsqrtf(v_[col] + 1e-5f)) + b_[col];
                    ((ushort*)outp)[(size_t)r * Nc + col] = f2h(fmaxf(y, 0.f) * 0.0625f);
                } else if (MODE == 2) {
                    ((float*)outp)[(size_t)r * Nc + col] = val + bias[col];
                } else {
                    float y = val + ar[col];
                    y = (y - m_[col]) * (g_[col] * rsqrtf(v_[col] + 1e-5f)) + b_[col];
                    ((ushort*)outp)[(size_t)r * Nc + col] = f2h(fmaxf(y, 0.f) * 0.0625f);
                }
            }
        }
    }
}

// pool chunk rows into pooled[g]: one wave per graph, atomics only for straddlers
__global__ void k_pool(const ushort* __restrict__ t, const int* __restrict__ gstart,
                       float* __restrict__ pooled, int c0) {
    int g = blockIdx.x * 4 + (threadIdx.x >> 6);
    int lane = threadIdx.x & 63;
    int gs = gstart[g], ge = gstart[g + 1];
    int lo = gs > c0 ? gs : c0;
    int hi = ge < c0 + CCH ? ge : c0 + CCH;
    if (lo >= hi) return;
    float4 s = make_float4(0.f, 0.f, 0.f, 0.f);
    for (int r = lo; r < hi; ++r) {
        ushort4 u = *(const ushort4*)(t + (size_t)(r - c0) * 256 + lane * 4);
        s.x += h2f(u.x); s.y += h2f(u.y); s.z += h2f(u.z); s.w += h2f(u.w);
    }
    s.x *= 16.f; s.y *= 16.f; s.z *= 16.f; s.w *= 16.f;
    float* p = pooled + (size_t)g * 256 + lane * 4;
    if (gs >= c0 && ge <= c0 + CCH) {
        *(float4*)p = s;
    } else {
        atomicAdd(p + 0, s.x); atomicAdd(p + 1, s.y);
        atomicAdd(p + 2, s.z); atomicAdd(p + 3, s.w);
    }
}

// ---------------- small f32 GEMM (GEMM3a, GEMM4) ----------------
enum { A_PLAIN = 0 };
enum { E_BIAS = 0, E_BNRELU = 1 };
template <int EMODE>
__global__ void __launch_bounds__(256)
gemm_k(const void* __restrict__ Av, const float* __restrict__ B,
       const float* __restrict__ bias,
       const float* __restrict__ g_, const float* __restrict__ b_,
       const float* __restrict__ m_, const float* __restrict__ v_,
       void* __restrict__ outv, int K, int Nc) {
    __shared__ float As[64][33];
    __shared__ float Bs[32][64];
    const int tid = threadIdx.x;
    const int row0 = blockIdx.x * 64;
    const int col0 = blockIdx.y * 64;
    float acc[4][4] = {};
    const int tx = tid & 15, ty = tid >> 4;
    for (int k0 = 0; k0 < K; k0 += 32) {
#pragma unroll
        for (int p = 0; p < 2; ++p) {
            int idx = p * 256 + tid;
            {
                int r = idx >> 3, c = (idx & 7) << 2;
                size_t aoff = (size_t)(row0 + r) * K + k0 + c;
                float4 va = *(const float4*)((const float*)Av + aoff);
                As[r][c + 0] = va.x; As[r][c + 1] = va.y;
                As[r][c + 2] = va.z; As[r][c + 3] = va.w;
            }
            {
                int kr = idx >> 4, cc = (idx & 15) << 2;
                *(float4*)&Bs[kr][cc] =
                    *(const float4*)(B + (size_t)(k0 + kr) * Nc + col0 + cc);
            }
        }
        __syncthreads();
#pragma unroll
        for (int k = 0; k < 32; ++k) {
            float4 bv = *(const float4*)&Bs[k][tx << 2];
            float a0 = As[ty * 4 + 0][k];
            float a1 = As[ty * 4 + 1][k];
            float a2 = As[ty * 4 + 2][k];
            float a3 = As[ty * 4 + 3][k];
            acc[0][0] += a0 * bv.x; acc[0][1] += a0 * bv.y; acc[0][2] += a0 * bv.z; acc[0][3] += a0 * bv.w;
            acc[1][0] += a1 * bv.x; acc[1][1] += a1 * bv.y; acc[1][2] += a1 * bv.z; acc[1][3] += a1 * bv.w;
            acc[2][0] += a2 * bv.x; acc[2][1] += a2 * bv.y; acc[2][2] += a2 * bv.z; acc[2][3] += a2 * bv.w;
            acc[3][0] += a3 * bv.x; acc[3][1] += a3 * bv.y; acc[3][2] += a3 * bv.z; acc[3][3] += a3 * bv.w;
        }
        __syncthreads();
    }
#pragma unroll
    for (int j = 0; j < 4; ++j) {
        int gr = row0 + ty * 4 + j;
        float vals[4];
#pragma unroll
        for (int l = 0; l < 4; ++l) {
            int gc = col0 + (tx << 2) + l;
            float val = acc[j][l];
            if (EMODE == E_BIAS) {
                vals[l] = val + bias[gc];
            } else {
                float y = val + bias[gc];
                float s = g_[gc] * rsqrtf(v_[gc] + 1e-5f);
                y = (y - m_[gc]) * s + b_[gc];
                vals[l] = fmaxf(y, 0.f);
            }
        }
        *(float4*)((float*)outv + (size_t)gr * Nc + col0 + (tx << 2)) =
            make_float4(vals[0], vals[1], vals[2], vals[3]);
    }
}

// ---------------- final head ----------------
__global__ void k_final(const float* __restrict__ vn, const float* __restrict__ pW1,
                        const float* __restrict__ pb1, const float* __restrict__ pW2,
                        const float* __restrict__ pb2, float* __restrict__ out) {
    int g = blockIdx.x;
    int j = threadIdx.x;
    __shared__ float vrow[HH];
    __shared__ float red[HH];
    vrow[j] = vn[(size_t)g * HH + j];
    __syncthreads();
    float acc = pb1[j];
    for (int k = 0; k < HH; ++k) acc = fmaf(vrow[k], pW1[k * HH + j], acc);
    red[j] = fmaxf(acc, 0.f) * pW2[j];
    __syncthreads();
    for (int s = 64; s > 0; s >>= 1) {
        if (j < s) red[j] += red[j + s];
        __syncthreads();
    }
    if (j == 0) out[g] = fminf(fmaxf(red[0] + pb2[0], 0.f), 50.f);
}

extern "C" void kernel_launch(void* const* d_in, const int* in_sizes, int n_in,
                              void* d_out, int out_size, void* d_ws, size_t ws_size,
                              hipStream_t stream) {
    const int*   x        = (const int*)  d_in[0];
    const int*   ei       = (const int*)  d_in[1];
    const int*   ea       = (const int*)  d_in[2];
    const int*   batch    = (const int*)  d_in[3];
    const float* atom_emb = (const float*)d_in[4];
    const float* vn_emb   = (const float*)d_in[5];
    const float* bond_emb = (const float*)d_in[6];
    const float* conv_eps = (const float*)d_in[7];
    const float* conv_W1  = (const float*)d_in[8];
    const float* conv_b1  = (const float*)d_in[9];
    const float* cbn_g    = (const float*)d_in[10];
    const float* cbn_b    = (const float*)d_in[11];
    const float* cbn_m    = (const float*)d_in[12];
    const float* cbn_v    = (const float*)d_in[13];
    const float* conv_W2  = (const float*)d_in[14];
    const float* conv_b2  = (const float*)d_in[15];
    const float* vn1_W    = (const float*)d_in[16];
    const float* vn1_b    = (const float*)d_in[17];
    const float* vn1_g    = (const float*)d_in[18];
    const float* vn1_be   = (const float*)d_in[19];
    const float* vn1_m    = (const float*)d_in[20];
    const float* vn1_v    = (const float*)d_in[21];
    const float* vn2_W    = (const float*)d_in[22];
    const float* vn2_b    = (const float*)d_in[23];
    const float* vn2_g    = (const float*)d_in[24];
    const float* vn2_be   = (const float*)d_in[25];
    const float* vn2_m    = (const float*)d_in[26];
    const float* vn2_v    = (const float*)d_in[27];
    const float* pW1      = (const float*)d_in[28];
    const float* pb1      = (const float*)d_in[29];
    const float* pW2      = (const float*)d_in[30];
    const float* pb2      = (const float*)d_in[31];

    // ---- workspace layout (~245.9 MB) ----
    char* base = (char*)d_ws;
    float*    h      = (float*)base;                                  // NN*HH f32
    ushort*   agg    = (ushort*)(base + (size_t)NN * HH * 4);         // NN*HH fp16
    ushort*   zc     = agg + (size_t)NN * HH;                         // CCH*256 fp16 (z / t)
    unsigned* packed = (unsigned*)(zc + (size_t)CCH * 256);           // EE u32
    int*      rowptr = (int*)(packed + EE);                           // NN+4
    int*      fill   = rowptr + NN + 4;                               // NN
    float*    ctab   = (float*)(fill + NN);                           // 512*HH f32
    int*      sums   = (int*)(ctab + 512 * HH);                       // 256
    int*      gstart = sums + 256;                                    // GG+4
    ushort*   W1t    = (ushort*)(gstart + GG + 4);                    // 256*128
    ushort*   W2t    = W1t + 256 * 128;                               // 128*256
    ushort*   W3t    = W2t + 128 * 256;                               // 256*128
    float*    vn     = (float*)(W3t + 256 * 128);                     // GG*HH
    float*    vnW    = vn + (size_t)GG * HH;                          // GG*256
    float*    pooled = vnW + (size_t)GG * 256;                        // GG*256
    float*    out    = (float*)d_out;

    // ---- setup ----
    k_zero<<<256, 256, 0, stream>>>((float*)fill);
    k_hist<<<EE / 256, 256, 0, stream>>>(ei, fill);
    k_scan1<<<256, 256, 0, stream>>>(fill, rowptr, sums);
    k_scan2<<<1, 256, 0, stream>>>(sums);
    k_scan3<<<256, 256, 0, stream>>>(rowptr, sums, fill);
    k_scatter<<<EE / 256, 256, 0, stream>>>(ei, ea, fill, packed);
    k_gstart<<<NN / 256, 256, 0, stream>>>(batch, gstart);
    k_atom<<<NN * 32 / 256, 256, 0, stream>>>(x, atom_emb, h);
    k_init_vn<<<GG * HH / 4 / 256, 256, 0, stream>>>(vn_emb, vn);

    for (int i = 0; i < 4; ++i) {
        k_ctab<<<64, 256, 0, stream>>>(bond_emb + (size_t)i * FBc * VBc * HH, ctab);
        k_agg<<<NN / 4, 256, 0, stream>>>(h, vn, batch, rowptr, packed, ctab, agg);
        // weight transposes (fp16 [N][K])
        k_wt<<<128, 256, 0, stream>>>(conv_W1 + (size_t)i * HH * 256, W1t, 7, 256);
        k_wt<<<128, 256, 0, stream>>>(conv_W2 + (size_t)i * 256 * HH, W2t, 8, 128);
        k_wt<<<128, 256, 0, stream>>>(vn1_W + (size_t)i * 256 * 256 + 128 * 256, W3t, 7, 256);

        // conv MLP, chunked
        for (int c0 = 0; c0 < NN; c0 += CCH) {
            dim3 g1(CCH / 128, 4);
            mfma_gemm<1><<<g1, 256, 0, stream>>>(
                h + (size_t)c0 * HH, agg + (size_t)c0 * HH, W1t, batch + c0, vn,
                conv_eps + i, conv_b1 + i * 256,
                cbn_g + i * 256, cbn_b + i * 256, cbn_m + i * 256, cbn_v + i * 256,
                zc, HH, 256);
            dim3 g2(CCH / 128, 2);
            mfma_gemm<2><<<g2, 256, 0, stream>>>(
                nullptr, zc, W2t, nullptr, nullptr, nullptr, conv_b2 + i * HH,
                nullptr, nullptr, nullptr, nullptr,
                h + (size_t)c0 * HH, 256, HH);
        }

        // GEMM3a: vnW = vn @ vn1_W[:128] + vn1_b
        {
            dim3 g3(GG / 64, 4);
            gemm_k<E_BIAS><<<g3, 256, 0, stream>>>(
                vn, vn1_W + (size_t)i * 256 * 256, vn1_b + i * 256,
                nullptr, nullptr, nullptr, nullptr, vnW, HH, 256);
        }
        k_zero<<<GG * 256 / 4 / 256, 256, 0, stream>>>(pooled);
        // GEMM3b + pool, chunked: t = relu(bn(h@W3 + vnW[batch])); pooled = segsum(t)
        for (int c0 = 0; c0 < NN; c0 += CCH) {
            dim3 g3b(CCH / 128, 4);
            mfma_gemm<3><<<g3b, 256, 0, stream>>>(
                h + (size_t)c0 * HH, nullptr, W3t, batch + c0, vnW,
                nullptr, nullptr,
                vn1_g + i * 256, vn1_be + i * 256, vn1_m + i * 256, vn1_v + i * 256,
                zc, HH, 256);
            k_pool<<<GG / 4, 256, 0, stream>>>(zc, gstart, pooled, c0);
        }
        // GEMM4: vn = relu(bn(pooled @ vn2_W + vn2_b))
        {
            dim3 g4(GG / 64, 2);
            gemm_k<E_BNRELU><<<g4, 256, 0, stream>>>(
                pooled, vn2_W + (size_t)i * 256 * HH, vn2_b + i * HH,
                vn2_g + i * HH, vn2_be + i * HH, vn2_m + i * HH, vn2_v + i * HH,
                vn, 256, HH);
        }
    }
    k_final<<<GG, 128, 0, stream>>>(vn, pW1, pb1, pW2, pb2, out);
}

// Round 8
// 2110.437 us; speedup vs baseline: 7.0779x; 1.5690x over previous
//
#include <hip/hip_runtime.h>
#include <hip/hip_fp16.h>

#define NN 262144
#define EE 1048576
#define GG 8192
#define HH 128
#define FBc 3
#define VAc 64
#define VBc 8
#define FAc 9

typedef _Float16 f16;
typedef _Float16 f16x8 __attribute__((ext_vector_type(8)));
typedef float f32x4 __attribute__((ext_vector_type(4)));

__device__ __forceinline__ float h2f(ushort u) {
    __half h; *(ushort*)&h = u; return __half2float(h);
}
__device__ __forceinline__ ushort f2h(float f) {
    __half h = __float2half_rn(f); return *(ushort*)&h;
}

// ---------------- zero fill ----------------
__global__ void k_zero(float* __restrict__ p) {
    size_t i = (size_t)(blockIdx.x * 256 + threadIdx.x) * 4;
    *(float4*)(p + i) = make_float4(0.f, 0.f, 0.f, 0.f);
}

// ---------------- atom encoder ----------------
__global__ void k_atom(const int* __restrict__ x, const float* __restrict__ emb,
                       float* __restrict__ h) {
    int t = blockIdx.x * 256 + threadIdx.x;
    int n = t >> 5, c = (t & 31) << 2;
    if (n >= NN) return;
    float4 a = make_float4(0.f, 0.f, 0.f, 0.f);
#pragma unroll
    for (int f = 0; f < FAc; ++f) {
        int v = x[n * FAc + f];
        float4 e = *(const float4*)(emb + ((size_t)(f * VAc + v)) * HH + c);
        a.x += e.x; a.y += e.y; a.z += e.z; a.w += e.w;
    }
    *(float4*)(h + (size_t)n * HH + c) = a;
}

// ---------------- vn init ----------------
__global__ void k_init_vn(const float* __restrict__ vn_emb, float* __restrict__ vn) {
    int t = blockIdx.x * 256 + threadIdx.x;
    int g = t >> 5, c = (t & 31) << 2;
    *(float4*)(vn + (size_t)g * HH + c) = *(const float4*)(vn_emb + c);
}

// ================= CSR build =================
__global__ void k_hist(const int* __restrict__ ei, int* __restrict__ deg) {
    int e = blockIdx.x * 256 + threadIdx.x;
    atomicAdd(&deg[ei[EE + e]], 1);
}
__global__ void k_scan1(const int* __restrict__ deg, int* __restrict__ rowptr,
                        int* __restrict__ sums) {
    __shared__ int s[256];
    int base = blockIdx.x * 1024 + threadIdx.x * 4;
    int4 d = *(const int4*)(deg + base);
    int t = d.x + d.y + d.z + d.w;
    s[threadIdx.x] = t;
    __syncthreads();
    for (int off = 1; off < 256; off <<= 1) {
        int v = (threadIdx.x >= off) ? s[threadIdx.x - off] : 0;
        __syncthreads();
        s[threadIdx.x] += v;
        __syncthreads();
    }
    int excl = s[threadIdx.x] - t;
    int4 o; o.x = excl; o.y = excl + d.x; o.z = o.y + d.y; o.w = o.z + d.z;
    *(int4*)(rowptr + base) = o;
    if (threadIdx.x == 255) sums[blockIdx.x] = s[255];
}
__global__ void k_scan2(int* __restrict__ sums) {
    __shared__ int s[256];
    int t = sums[threadIdx.x];
    s[threadIdx.x] = t;
    __syncthreads();
    for (int off = 1; off < 256; off <<= 1) {
        int v = (threadIdx.x >= off) ? s[threadIdx.x - off] : 0;
        __syncthreads();
        s[threadIdx.x] += v;
        __syncthreads();
    }
    sums[threadIdx.x] = s[threadIdx.x] - t;
}
__global__ void k_scan3(int* __restrict__ rowptr, const int* __restrict__ sums,
                        int* __restrict__ fill) {
    int base = blockIdx.x * 1024 + threadIdx.x * 4;
    int add = sums[blockIdx.x];
    int4 r = *(const int4*)(rowptr + base);
    r.x += add; r.y += add; r.z += add; r.w += add;
    *(int4*)(rowptr + base) = r;
    *(int4*)(fill + base) = r;
    if (blockIdx.x == 0 && threadIdx.x == 0) rowptr[NN] = EE;
}
__global__ void k_scatter(const int* __restrict__ ei, const int* __restrict__ ea,
                          int* __restrict__ fill, unsigned* __restrict__ packed) {
    int e = blockIdx.x * 256 + threadIdx.x;
    int dst = ei[EE + e];
    int pos = atomicAdd(&fill[dst], 1);
    unsigned cb = (unsigned)(ea[e * 3 + 0] + ea[e * 3 + 1] * 8 + ea[e * 3 + 2] * 64);
    packed[pos] = (unsigned)ei[e] | (cb << 18);
}

// per-layer bond-combo table
__global__ void k_ctab(const float* __restrict__ bemb, float* __restrict__ ctab) {
    int t = blockIdx.x * 256 + threadIdx.x;
    int cb = t >> 5, c = (t & 31) << 2;
    int a0 = cb & 7, a1 = (cb >> 3) & 7, a2 = cb >> 6;
    float4 b0 = *(const float4*)(bemb + (size_t)(0 * VBc + a0) * HH + c);
    float4 b1 = *(const float4*)(bemb + (size_t)(1 * VBc + a1) * HH + c);
    float4 b2 = *(const float4*)(bemb + (size_t)(2 * VBc + a2) * HH + c);
    float4 o = make_float4(b0.x + b1.x + b2.x, b0.y + b1.y + b2.y,
                           b0.z + b1.z + b2.z, b0.w + b1.w + b2.w);
    *(float4*)(ctab + (size_t)cb * HH + c) = o;
}

// weight transpose: W [K][Nsrc] f32 -> Wt [N][K] fp16
__global__ void k_wt(const float* __restrict__ W, ushort* __restrict__ Wt, int lk, int Nsrc) {
    int o = blockIdx.x * 256 + threadIdx.x;
    int K = 1 << lk;
    int c = o >> lk, k = o & (K - 1);
    Wt[o] = f2h(W[(size_t)k * Nsrc + c]);
}

// CSR aggregation: agg[n] = (1/16) sum relu(h[src]+vn[batch[src]]+ctab)
__global__ void k_agg(const float* __restrict__ h, const float* __restrict__ vn,
                      const int* __restrict__ batch,
                      const int* __restrict__ rowptr, const unsigned* __restrict__ packed,
                      const float* __restrict__ ctab, ushort* __restrict__ agg) {
    int n = blockIdx.x * 4 + (threadIdx.x >> 6);
    int lane = threadIdx.x & 63;
    int beg = rowptr[n], end = rowptr[n + 1];
    float a0 = 0.f, a1 = 0.f;
    for (int i = beg; i < end; ++i) {
        unsigned p = packed[i];
        int src = p & 0x3FFFF;
        int cb = p >> 18;
        float2 hv = *(const float2*)(h + (size_t)src * HH + lane * 2);
        float2 vv = *(const float2*)(vn + (size_t)batch[src] * HH + lane * 2);
        float2 ct = *(const float2*)(ctab + (size_t)cb * HH + lane * 2);
        a0 += fmaxf(hv.x + vv.x + ct.x, 0.f);
        a1 += fmaxf(hv.y + vv.y + ct.y, 0.f);
    }
    ushort2 o; o.x = f2h(a0 * 0.0625f); o.y = f2h(a1 * 0.0625f);
    *(ushort2*)(agg + (size_t)n * HH + lane * 2) = o;
}

// ============== fused conv MLP: one launch, z stays in LDS ==============
// z = relu(bn(((1+eps)(h+vn[batch])+agg) @ W1 + b1));  h = z @ W2 + b2
__global__ void __launch_bounds__(512)
k_conv(float* __restrict__ hio, const ushort* __restrict__ agg,
       const ushort* __restrict__ W1t, const ushort* __restrict__ W2t,
       const int* __restrict__ batch, const float* __restrict__ vn,
       const float* __restrict__ eps_ptr, const float* __restrict__ b1,
       const float* __restrict__ g1v, const float* __restrict__ be1,
       const float* __restrict__ m1, const float* __restrict__ v1,
       const float* __restrict__ b2) {
    __shared__ ushort As[128][136];   // A/16 fp16, K=128   (34.8 KB)
    __shared__ ushort zs[128][264];   // z/16 fp16, 256 cols (67.6 KB)
    __shared__ ushort Wb[128][136];   // weight tile buffer  (34.8 KB)
    __shared__ int batchL[128];
    const int tid = threadIdx.x;
    const int r0 = blockIdx.x * 128;
    const int w = tid >> 6, l = tid & 63, lr = l & 15, lg = l >> 4;
    if (tid < 128) batchL[tid] = batch[r0 + tid];
    const float eps1 = 1.f + eps_ptr[0];
    __syncthreads();

    // ---- stage A = (eps1*(h+vn) )/16 + agg_st ----
    {
        int row = tid >> 2, q = tid & 3;
        const float* hp = hio + (size_t)(r0 + row) * HH + q * 32;
        const float* vp = vn + (size_t)batchL[row] * HH + q * 32;
        const ushort* ap = agg + (size_t)(r0 + row) * HH + q * 32;
#pragma unroll
        for (int j4 = 0; j4 < 4; ++j4) {
            f16x8 u = *(const f16x8*)(ap + j4 * 8);
            f16x8 o;
#pragma unroll
            for (int j = 0; j < 8; ++j) {
                float hv = hp[j4 * 8 + j] + vp[j4 * 8 + j];
                o[j] = (f16)(eps1 * hv * 0.0625f + (float)u[j]);
            }
            *(f16x8*)&As[row][q * 32 + j4 * 8] = o;
        }
    }

    // ---- phase A: z = relu(bn(A@W1*16 + b1)) in 2 col-halves ----
    for (int ch = 0; ch < 2; ++ch) {
        __syncthreads();
        {   // stage W1 half: 128 outcols x 128 K
            int c = tid >> 2, q = tid & 3;
            const ushort* wp = W1t + (size_t)(ch * 128 + c) * HH + q * 32;
#pragma unroll
            for (int j4 = 0; j4 < 4; ++j4)
                *(f16x8*)&Wb[c][q * 32 + j4 * 8] = *(const f16x8*)(wp + j4 * 8);
        }
        __syncthreads();
        f32x4 acc[8] = {};
#pragma unroll
        for (int k0 = 0; k0 < 128; k0 += 32) {
            f16x8 af = *(const f16x8*)&As[w * 16 + lr][k0 + lg * 8];
#pragma unroll
            for (int fc = 0; fc < 8; ++fc) {
                f16x8 bf = *(const f16x8*)&Wb[fc * 16 + lr][k0 + lg * 8];
                acc[fc] = __builtin_amdgcn_mfma_f32_16x16x32_f16(af, bf, acc[fc], 0, 0, 0);
            }
        }
#pragma unroll
        for (int fc = 0; fc < 8; ++fc) {
#pragma unroll
            for (int reg = 0; reg < 4; ++reg) {
                int rl = w * 16 + lg * 4 + reg;
                int col = ch * 128 + fc * 16 + lr;
                float val = acc[fc][reg] * 16.f + b1[col];
                float y = (val - m1[col]) * (g1v[col] * rsqrtf(v1[col] + 1e-5f)) + be1[col];
                zs[rl][col] = f2h(fmaxf(y, 0.f) * 0.0625f);
            }
        }
    }
    __syncthreads();

    // ---- phase B: h = z@W2*16 + b2 in 2 col-halves of 64 ----
    ushort(*Wb2)[264] = (ushort(*)[264]) & Wb[0][0];   // 64x264 fits in Wb
    for (int ch = 0; ch < 2; ++ch) {
        __syncthreads();
        {   // stage W2 half: 64 outcols x 256 K
            int c = tid >> 3, q = tid & 7;
            const ushort* wp = W2t + (size_t)(ch * 64 + c) * 256 + q * 32;
#pragma unroll
            for (int j4 = 0; j4 < 4; ++j4)
                *(f16x8*)&Wb2[c][q * 32 + j4 * 8] = *(const f16x8*)(wp + j4 * 8);
        }
        __syncthreads();
        f32x4 acc[4] = {};
#pragma unroll
        for (int k0 = 0; k0 < 256; k0 += 32) {
            f16x8 af = *(const f16x8*)&zs[w * 16 + lr][k0 + lg * 8];
#pragma unroll
            for (int fc = 0; fc < 4; ++fc) {
                f16x8 bf = *(const f16x8*)&Wb2[fc * 16 + lr][k0 + lg * 8];
                acc[fc] = __builtin_amdgcn_mfma_f32_16x16x32_f16(af, bf, acc[fc], 0, 0, 0);
            }
        }
#pragma unroll
        for (int fc = 0; fc < 4; ++fc) {
#pragma unroll
            for (int reg = 0; reg < 4; ++reg) {
                int rl = w * 16 + lg * 4 + reg;
                int col = ch * 64 + fc * 16 + lr;
                hio[(size_t)(r0 + rl) * HH + col] = acc[fc][reg] * 16.f + b2[col];
            }
        }
    }
}

// ============== fused vn1-bottom GEMM + BN/relu + segment pooling ==============
// t = relu(bn(h@W3*16 + vnW[batch])); pooled[g] += segsum(t)
__global__ void __launch_bounds__(512)
k_vnpool(const float* __restrict__ h, const ushort* __restrict__ W3t,
         const int* __restrict__ batch, const float* __restrict__ vnW,
         const float* __restrict__ g_, const float* __restrict__ be_,
         const float* __restrict__ m_, const float* __restrict__ v_,
         float* __restrict__ pooled) {
    __shared__ ushort As[128][136];
    __shared__ ushort Wb[128][136];
    __shared__ ushort ts[128][136];
    __shared__ int batchL[128];
    const int tid = threadIdx.x;
    const int r0 = blockIdx.x * 128;
    const int w = tid >> 6, l = tid & 63, lr = l & 15, lg = l >> 4;
    if (tid < 128) batchL[tid] = batch[r0 + tid];
    __syncthreads();
    {   // stage A = h/16
        int row = tid >> 2, q = tid & 3;
        const float* hp = h + (size_t)(r0 + row) * HH + q * 32;
#pragma unroll
        for (int j4 = 0; j4 < 4; ++j4) {
            f16x8 o;
#pragma unroll
            for (int j = 0; j < 8; ++j) o[j] = (f16)(hp[j4 * 8 + j] * 0.0625f);
            *(f16x8*)&As[row][q * 32 + j4 * 8] = o;
        }
    }
    for (int ch = 0; ch < 2; ++ch) {
        __syncthreads();
        {   // stage W3 half: 128 outcols x 128 K
            int c = tid >> 2, q = tid & 3;
            const ushort* wp = W3t + (size_t)(ch * 128 + c) * HH + q * 32;
#pragma unroll
            for (int j4 = 0; j4 < 4; ++j4)
                *(f16x8*)&Wb[c][q * 32 + j4 * 8] = *(const f16x8*)(wp + j4 * 8);
        }
        __syncthreads();
        f32x4 acc[8] = {};
#pragma unroll
        for (int k0 = 0; k0 < 128; k0 += 32) {
            f16x8 af = *(const f16x8*)&As[w * 16 + lr][k0 + lg * 8];
#pragma unroll
            for (int fc = 0; fc < 8; ++fc) {
                f16x8 bf = *(const f16x8*)&Wb[fc * 16 + lr][k0 + lg * 8];
                acc[fc] = __builtin_amdgcn_mfma_f32_16x16x32_f16(af, bf, acc[fc], 0, 0, 0);
            }
        }
#pragma unroll
        for (int fc = 0; fc < 8; ++fc) {
#pragma unroll
            for (int reg = 0; reg < 4; ++reg) {
                int rl = w * 16 + lg * 4 + reg;
                int colg = ch * 128 + fc * 16 + lr;
                int gg = batchL[rl];
                float val = acc[fc][reg] * 16.f + vnW[(size_t)gg * 256 + colg];
                float y = (val - m_[colg]) * (g_[colg] * rsqrtf(v_[colg] + 1e-5f)) + be_[colg];
                ts[rl][fc * 16 + lr] = f2h(fmaxf(y, 0.f) * 0.0625f);
            }
        }
        __syncthreads();
        {   // segment pooling: thread -> col (0..127), row-chunk of 32
            int col = tid & 127, rs = (tid >> 7) * 32;
            float s = 0.f;
            int cur = batchL[rs];
            for (int r = rs; r < rs + 32; ++r) {
                int gg = batchL[r];
                if (gg != cur) {
                    atomicAdd(&pooled[(size_t)cur * 256 + ch * 128 + col], s * 16.f);
                    s = 0.f; cur = gg;
                }
                s += h2f(ts[r][col]);
            }
            atomicAdd(&pooled[(size_t)cur * 256 + ch * 128 + col], s * 16.f);
        }
    }
}

// ---------------- small f32 GEMM (GEMM3a, GEMM4) ----------------
enum { E_BIAS = 0, E_BNRELU = 1 };
template <int EMODE>
__global__ void __launch_bounds__(256)
gemm_k(const void* __restrict__ Av, const float* __restrict__ B,
       const float* __restrict__ bias,
       const float* __restrict__ g_, const float* __restrict__ b_,
       const float* __restrict__ m_, const float* __restrict__ v_,
       void* __restrict__ outv, int K, int Nc) {
    __shared__ float As[64][33];
    __shared__ float Bs[32][64];
    const int tid = threadIdx.x;
    const int row0 = blockIdx.x * 64;
    const int col0 = blockIdx.y * 64;
    float acc[4][4] = {};
    const int tx = tid & 15, ty = tid >> 4;
    for (int k0 = 0; k0 < K; k0 += 32) {
#pragma unroll
        for (int p = 0; p < 2; ++p) {
            int idx = p * 256 + tid;
            {
                int r = idx >> 3, c = (idx & 7) << 2;
                size_t aoff = (size_t)(row0 + r) * K + k0 + c;
                float4 va = *(const float4*)((const float*)Av + aoff);
                As[r][c + 0] = va.x; As[r][c + 1] = va.y;
                As[r][c + 2] = va.z; As[r][c + 3] = va.w;
            }
            {
                int kr = idx >> 4, cc = (idx & 15) << 2;
                *(float4*)&Bs[kr][cc] =
                    *(const float4*)(B + (size_t)(k0 + kr) * Nc + col0 + cc);
            }
        }
        __syncthreads();
#pragma unroll
        for (int k = 0; k < 32; ++k) {
            float4 bv = *(const float4*)&Bs[k][tx << 2];
            float a0 = As[ty * 4 + 0][k];
            float a1 = As[ty * 4 + 1][k];
            float a2 = As[ty * 4 + 2][k];
            float a3 = As[ty * 4 + 3][k];
            acc[0][0] += a0 * bv.x; acc[0][1] += a0 * bv.y; acc[0][2] += a0 * bv.z; acc[0][3] += a0 * bv.w;
            acc[1][0] += a1 * bv.x; acc[1][1] += a1 * bv.y; acc[1][2] += a1 * bv.z; acc[1][3] += a1 * bv.w;
            acc[2][0] += a2 * bv.x; acc[2][1] += a2 * bv.y; acc[2][2] += a2 * bv.z; acc[2][3] += a2 * bv.w;
            acc[3][0] += a3 * bv.x; acc[3][1] += a3 * bv.y; acc[3][2] += a3 * bv.z; acc[3][3] += a3 * bv.w;
        }
        __syncthreads();
    }
#pragma unroll
    for (int j = 0; j < 4; ++j) {
        int gr = row0 + ty * 4 + j;
        float vals[4];
#pragma unroll
        for (int lx = 0; lx < 4; ++lx) {
            int gc = col0 + (tx << 2) + lx;
            float val = acc[j][lx];
            if (EMODE == E_BIAS) {
                vals[lx] = val + bias[gc];
            } else {
                float y = val + bias[gc];
                float s = g_[gc] * rsqrtf(v_[gc] + 1e-5f);
                y = (y - m_[gc]) * s + b_[gc];
                vals[lx] = fmaxf(y, 0.f);
            }
        }
        *(float4*)((float*)outv + (size_t)gr * Nc + col0 + (tx << 2)) =
            make_float4(vals[0], vals[1], vals[2], vals[3]);
    }
}

// ---------------- final head ----------------
__global__ void k_final(const float* __restrict__ vn, const float* __restrict__ pW1,
                        const float* __restrict__ pb1, const float* __restrict__ pW2,
                        const float* __restrict__ pb2, float* __restrict__ out) {
    int g = blockIdx.x;
    int j = threadIdx.x;
    __shared__ float vrow[HH];
    __shared__ float red[HH];
    vrow[j] = vn[(size_t)g * HH + j];
    __syncthreads();
    float acc = pb1[j];
    for (int k = 0; k < HH; ++k) acc = fmaf(vrow[k], pW1[k * HH + j], acc);
    red[j] = fmaxf(acc, 0.f) * pW2[j];
    __syncthreads();
    for (int s = 64; s > 0; s >>= 1) {
        if (j < s) red[j] += red[j + s];
        __syncthreads();
    }
    if (j == 0) out[g] = fminf(fmaxf(red[0] + pb2[0], 0.f), 50.f);
}

extern "C" void kernel_launch(void* const* d_in, const int* in_sizes, int n_in,
                              void* d_out, int out_size, void* d_ws, size_t ws_size,
                              hipStream_t stream) {
    const int*   x        = (const int*)  d_in[0];
    const int*   ei       = (const int*)  d_in[1];
    const int*   ea       = (const int*)  d_in[2];
    const int*   batch    = (const int*)  d_in[3];
    const float* atom_emb = (const float*)d_in[4];
    const float* vn_emb   = (const float*)d_in[5];
    const float* bond_emb = (const float*)d_in[6];
    const float* conv_eps = (const float*)d_in[7];
    const float* conv_W1  = (const float*)d_in[8];
    const float* conv_b1  = (const float*)d_in[9];
    const float* cbn_g    = (const float*)d_in[10];
    const float* cbn_b    = (const float*)d_in[11];
    const float* cbn_m    = (const float*)d_in[12];
    const float* cbn_v    = (const float*)d_in[13];
    const float* conv_W2  = (const float*)d_in[14];
    const float* conv_b2  = (const float*)d_in[15];
    const float* vn1_W    = (const float*)d_in[16];
    const float* vn1_b    = (const float*)d_in[17];
    const float* vn1_g    = (const float*)d_in[18];
    const float* vn1_be   = (const float*)d_in[19];
    const float* vn1_m    = (const float*)d_in[20];
    const float* vn1_v    = (const float*)d_in[21];
    const float* vn2_W    = (const float*)d_in[22];
    const float* vn2_b    = (const float*)d_in[23];
    const float* vn2_g    = (const float*)d_in[24];
    const float* vn2_be   = (const float*)d_in[25];
    const float* vn2_m    = (const float*)d_in[26];
    const float* vn2_v    = (const float*)d_in[27];
    const float* pW1      = (const float*)d_in[28];
    const float* pb1      = (const float*)d_in[29];
    const float* pW2      = (const float*)d_in[30];
    const float* pb2      = (const float*)d_in[31];

    // ---- workspace layout (~229 MB) ----
    char* base = (char*)d_ws;
    float*    h      = (float*)base;                                  // NN*HH f32
    ushort*   agg    = (ushort*)(base + (size_t)NN * HH * 4);         // NN*HH fp16
    unsigned* packed = (unsigned*)(agg + (size_t)NN * HH);            // EE u32
    int*      rowptr = (int*)(packed + EE);                           // NN+4
    int*      fill   = rowptr + NN + 4;                               // NN
    float*    ctab   = (float*)(fill + NN);                           // 512*HH f32
    int*      sums   = (int*)(ctab + 512 * HH);                       // 256
    ushort*   W1t    = (ushort*)(sums + 256);                         // 256*128
    ushort*   W2t    = W1t + 256 * 128;                               // 128*256
    ushort*   W3t    = W2t + 128 * 256;                               // 256*128
    float*    vn     = (float*)(W3t + 256 * 128);                     // GG*HH
    float*    vnW    = vn + (size_t)GG * HH;                          // GG*256
    float*    pooled = vnW + (size_t)GG * 256;                        // GG*256
    float*    out    = (float*)d_out;

    // ---- setup ----
    k_zero<<<256, 256, 0, stream>>>((float*)fill);
    k_hist<<<EE / 256, 256, 0, stream>>>(ei, fill);
    k_scan1<<<256, 256, 0, stream>>>(fill, rowptr, sums);
    k_scan2<<<1, 256, 0, stream>>>(sums);
    k_scan3<<<256, 256, 0, stream>>>(rowptr, sums, fill);
    k_scatter<<<EE / 256, 256, 0, stream>>>(ei, ea, fill, packed);
    k_atom<<<NN * 32 / 256, 256, 0, stream>>>(x, atom_emb, h);
    k_init_vn<<<GG * HH / 4 / 256, 256, 0, stream>>>(vn_emb, vn);

    for (int i = 0; i < 4; ++i) {
        k_ctab<<<64, 256, 0, stream>>>(bond_emb + (size_t)i * FBc * VBc * HH, ctab);
        k_agg<<<NN / 4, 256, 0, stream>>>(h, vn, batch, rowptr, packed, ctab, agg);
        k_wt<<<128, 256, 0, stream>>>(conv_W1 + (size_t)i * HH * 256, W1t, 7, 256);
        k_wt<<<128, 256, 0, stream>>>(conv_W2 + (size_t)i * 256 * HH, W2t, 8, 128);
        k_wt<<<128, 256, 0, stream>>>(vn1_W + (size_t)i * 256 * 256 + 128 * 256, W3t, 7, 256);

        // fused conv MLP (in-place h update)
        k_conv<<<NN / 128, 512, 0, stream>>>(
            h, agg, W1t, W2t, batch, vn, conv_eps + i,
            conv_b1 + i * 256, cbn_g + i * 256, cbn_b + i * 256,
            cbn_m + i * 256, cbn_v + i * 256, conv_b2 + i * HH);

        // GEMM3a: vnW = vn @ vn1_W[:128] + vn1_b
        {
            dim3 g3(GG / 64, 4);
            gemm_k<E_BIAS><<<g3, 256, 0, stream>>>(
                vn, vn1_W + (size_t)i * 256 * 256, vn1_b + i * 256,
                nullptr, nullptr, nullptr, nullptr, vnW, HH, 256);
        }
        k_zero<<<GG * 256 / 4 / 256, 256, 0, stream>>>(pooled);
        // fused GEMM3b + segment pooling
        k_vnpool<<<NN / 128, 512, 0, stream>>>(
            h, W3t, batch, vnW,
            vn1_g + i * 256, vn1_be + i * 256, vn1_m + i * 256, vn1_v + i * 256,
            pooled);
        // GEMM4: vn = relu(bn(pooled @ vn2_W + vn2_b))
        {
            dim3 g4(GG / 64, 2);
            gemm_k<E_BNRELU><<<g4, 256, 0, stream>>>(
                pooled, vn2_W + (size_t)i * 256 * HH, vn2_b + i * HH,
                vn2_g + i * HH, vn2_be + i * HH, vn2_m + i * HH, vn2_v + i * HH,
                vn, 256, HH);
        }
    }
    k_final<<<GG, 128, 0, stream>>>(vn, pW1, pb1, pW2, pb2, out);
}

// Round 9
// 1815.580 us; speedup vs baseline: 8.2274x; 1.1624x over previous
//
#include <hip/hip_runtime.h>
#include <hip/hip_fp16.h>

#define NN 262144
#define EE 1048576
#define GG 8192
#define HH 128
#define FBc 3
#define VAc 64
#define VBc 8
#define FAc 9

typedef _Float16 f16;
typedef _Float16 f16x8 __attribute__((ext_vector_type(8)));
typedef float f32x4 __attribute__((ext_vector_type(4)));

__device__ __forceinline__ float h2f(ushort u) {
    __half h; *(ushort*)&h = u; return __half2float(h);
}
__device__ __forceinline__ ushort f2h(float f) {
    __half h = __float2half_rn(f); return *(ushort*)&h;
}

// ---------------- zero fill ----------------
__global__ void k_zero(float* __restrict__ p) {
    size_t i = (size_t)(blockIdx.x * 256 + threadIdx.x) * 4;
    *(float4*)(p + i) = make_float4(0.f, 0.f, 0.f, 0.f);
}

// ---------------- atom encoder ----------------
__global__ void k_atom(const int* __restrict__ x, const float* __restrict__ emb,
                       float* __restrict__ h) {
    int t = blockIdx.x * 256 + threadIdx.x;
    int n = t >> 5, c = (t & 31) << 2;
    if (n >= NN) return;
    float4 a = make_float4(0.f, 0.f, 0.f, 0.f);
#pragma unroll
    for (int f = 0; f < FAc; ++f) {
        int v = x[n * FAc + f];
        float4 e = *(const float4*)(emb + ((size_t)(f * VAc + v)) * HH + c);
        a.x += e.x; a.y += e.y; a.z += e.z; a.w += e.w;
    }
    *(float4*)(h + (size_t)n * HH + c) = a;
}

// ---------------- vn init ----------------
__global__ void k_init_vn(const float* __restrict__ vn_emb, float* __restrict__ vn) {
    int t = blockIdx.x * 256 + threadIdx.x;
    int g = t >> 5, c = (t & 31) << 2;
    *(float4*)(vn + (size_t)g * HH + c) = *(const float4*)(vn_emb + c);
}

// ================= CSR build =================
__global__ void k_hist(const int* __restrict__ ei, int* __restrict__ deg) {
    int e = blockIdx.x * 256 + threadIdx.x;
    atomicAdd(&deg[ei[EE + e]], 1);
}
__global__ void k_scan1(const int* __restrict__ deg, int* __restrict__ rowptr,
                        int* __restrict__ sums) {
    __shared__ int s[256];
    int base = blockIdx.x * 1024 + threadIdx.x * 4;
    int4 d = *(const int4*)(deg + base);
    int t = d.x + d.y + d.z + d.w;
    s[threadIdx.x] = t;
    __syncthreads();
    for (int off = 1; off < 256; off <<= 1) {
        int v = (threadIdx.x >= off) ? s[threadIdx.x - off] : 0;
        __syncthreads();
        s[threadIdx.x] += v;
        __syncthreads();
    }
    int excl = s[threadIdx.x] - t;
    int4 o; o.x = excl; o.y = excl + d.x; o.z = o.y + d.y; o.w = o.z + d.z;
    *(int4*)(rowptr + base) = o;
    if (threadIdx.x == 255) sums[blockIdx.x] = s[255];
}
__global__ void k_scan2(int* __restrict__ sums) {
    __shared__ int s[256];
    int t = sums[threadIdx.x];
    s[threadIdx.x] = t;
    __syncthreads();
    for (int off = 1; off < 256; off <<= 1) {
        int v = (threadIdx.x >= off) ? s[threadIdx.x - off] : 0;
        __syncthreads();
        s[threadIdx.x] += v;
        __syncthreads();
    }
    sums[threadIdx.x] = s[threadIdx.x] - t;
}
__global__ void k_scan3(int* __restrict__ rowptr, const int* __restrict__ sums,
                        int* __restrict__ fill) {
    int base = blockIdx.x * 1024 + threadIdx.x * 4;
    int add = sums[blockIdx.x];
    int4 r = *(const int4*)(rowptr + base);
    r.x += add; r.y += add; r.z += add; r.w += add;
    *(int4*)(rowptr + base) = r;
    *(int4*)(fill + base) = r;
    if (blockIdx.x == 0 && threadIdx.x == 0) rowptr[NN] = EE;
}
__global__ void k_scatter(const int* __restrict__ ei, const int* __restrict__ ea,
                          int* __restrict__ fill, unsigned* __restrict__ packed) {
    int e = blockIdx.x * 256 + threadIdx.x;
    int dst = ei[EE + e];
    int pos = atomicAdd(&fill[dst], 1);
    unsigned cb = (unsigned)(ea[e * 3 + 0] + ea[e * 3 + 1] * 8 + ea[e * 3 + 2] * 64);
    packed[pos] = (unsigned)ei[e] | (cb << 18);
}

// per-layer bond-combo table
__global__ void k_ctab(const float* __restrict__ bemb, float* __restrict__ ctab) {
    int t = blockIdx.x * 256 + threadIdx.x;
    int cb = t >> 5, c = (t & 31) << 2;
    int a0 = cb & 7, a1 = (cb >> 3) & 7, a2 = cb >> 6;
    float4 b0 = *(const float4*)(bemb + (size_t)(0 * VBc + a0) * HH + c);
    float4 b1 = *(const float4*)(bemb + (size_t)(1 * VBc + a1) * HH + c);
    float4 b2 = *(const float4*)(bemb + (size_t)(2 * VBc + a2) * HH + c);
    float4 o = make_float4(b0.x + b1.x + b2.x, b0.y + b1.y + b2.y,
                           b0.z + b1.z + b2.z, b0.w + b1.w + b2.w);
    *(float4*)(ctab + (size_t)cb * HH + c) = o;
}

// weight transpose: W [K][Nsrc] f32 -> Wt [N][K] fp16
__global__ void k_wt(const float* __restrict__ W, ushort* __restrict__ Wt, int lk, int Nsrc) {
    int o = blockIdx.x * 256 + threadIdx.x;
    int K = 1 << lk;
    int c = o >> lk, k = o & (K - 1);
    Wt[o] = f2h(W[(size_t)k * Nsrc + c]);
}

// CSR aggregation (2-edge unrolled): agg[n] = (1/16) sum relu(h[src]+vn[batch[src]]+ctab)
__global__ void k_agg(const float* __restrict__ h, const float* __restrict__ vn,
                      const int* __restrict__ batch,
                      const int* __restrict__ rowptr, const unsigned* __restrict__ packed,
                      const float* __restrict__ ctab, ushort* __restrict__ agg) {
    int n = blockIdx.x * 4 + (threadIdx.x >> 6);
    int lane = threadIdx.x & 63;
    int co = lane * 2;
    int beg = rowptr[n], end = rowptr[n + 1];
    float a0 = 0.f, a1 = 0.f;
    int i = beg;
    for (; i + 1 < end; i += 2) {
        unsigned p0 = packed[i], p1 = packed[i + 1];
        int s0 = p0 & 0x3FFFF, s1 = p1 & 0x3FFFF;
        int c0 = p0 >> 18, c1 = p1 >> 18;
        float2 h0 = *(const float2*)(h + (size_t)s0 * HH + co);
        float2 h1 = *(const float2*)(h + (size_t)s1 * HH + co);
        float2 v0 = *(const float2*)(vn + (size_t)batch[s0] * HH + co);
        float2 v1 = *(const float2*)(vn + (size_t)batch[s1] * HH + co);
        float2 t0 = *(const float2*)(ctab + (size_t)c0 * HH + co);
        float2 t1 = *(const float2*)(ctab + (size_t)c1 * HH + co);
        a0 += fmaxf(h0.x + v0.x + t0.x, 0.f) + fmaxf(h1.x + v1.x + t1.x, 0.f);
        a1 += fmaxf(h0.y + v0.y + t0.y, 0.f) + fmaxf(h1.y + v1.y + t1.y, 0.f);
    }
    if (i < end) {
        unsigned p = packed[i];
        int src = p & 0x3FFFF, cb = p >> 18;
        float2 hv = *(const float2*)(h + (size_t)src * HH + co);
        float2 vv = *(const float2*)(vn + (size_t)batch[src] * HH + co);
        float2 ct = *(const float2*)(ctab + (size_t)cb * HH + co);
        a0 += fmaxf(hv.x + vv.x + ct.x, 0.f);
        a1 += fmaxf(hv.y + vv.y + ct.y, 0.f);
    }
    ushort2 o; o.x = f2h(a0 * 0.0625f); o.y = f2h(a1 * 0.0625f);
    *(ushort2*)(agg + (size_t)n * HH + co) = o;
}

// ============== mega-kernel: conv MLP + vn1-bottom + segment pool ==============
// A = ((1+eps)(h+vn[batch])+agg);  z = relu(bn(A@W1+b1));  h' = z@W2+b2  (-> global)
// t = relu(bn(h'@W3 + vnW[batch])); pooled[g] += segsum(t)   (t stays in LDS, f32)
__global__ void __launch_bounds__(512)
k_conv(float* __restrict__ hio, const ushort* __restrict__ agg,
       const ushort* __restrict__ W1t, const ushort* __restrict__ W2t,
       const ushort* __restrict__ W3t,
       const int* __restrict__ batch, const float* __restrict__ vn,
       const float* __restrict__ vnW,
       const float* __restrict__ eps_ptr, const float* __restrict__ b1,
       const float* __restrict__ g1v, const float* __restrict__ be1,
       const float* __restrict__ m1, const float* __restrict__ v1,
       const float* __restrict__ b2,
       const float* __restrict__ g3, const float* __restrict__ be3,
       const float* __restrict__ m3, const float* __restrict__ v3,
       float* __restrict__ pooled) {
    __shared__ ushort As[128][136];   // A/16 fp16 (34.8 KB); later h'/16 fp16
    __shared__ ushort zs[128][264];   // z/16 fp16 (67.6 KB); later ts f32 alias
    __shared__ ushort Wb[128][136];   // weight tile buffer (34.8 KB)
    __shared__ int batchL[128];
    float(*ts)[132] = (float(*)[132]) & zs[0][0];   // f32 alias, same 264-ushort pitch
    const int tid = threadIdx.x;
    const int r0 = blockIdx.x * 128;
    const int w = tid >> 6, l = tid & 63, lr = l & 15, lg = l >> 4;
    if (tid < 128) batchL[tid] = batch[r0 + tid];
    const float eps1 = 1.f + eps_ptr[0];
    __syncthreads();

    // ---- stage A = eps1*(h+vn)/16 + agg_st ----
    {
        int row = tid >> 2, q = tid & 3;
        const float* hp = hio + (size_t)(r0 + row) * HH + q * 32;
        const float* vp = vn + (size_t)batchL[row] * HH + q * 32;
        const ushort* ap = agg + (size_t)(r0 + row) * HH + q * 32;
#pragma unroll
        for (int j4 = 0; j4 < 4; ++j4) {
            f16x8 u = *(const f16x8*)(ap + j4 * 8);
            f16x8 o;
#pragma unroll
            for (int j = 0; j < 8; ++j) {
                float hv = hp[j4 * 8 + j] + vp[j4 * 8 + j];
                o[j] = (f16)(eps1 * hv * 0.0625f + (float)u[j]);
            }
            *(f16x8*)&As[row][q * 32 + j4 * 8] = o;
        }
    }

    // ---- phase A: z = relu(bn(A@W1*16 + b1)) in 2 col-halves ----
    for (int ch = 0; ch < 2; ++ch) {
        __syncthreads();
        {   // stage W1 half: 128 outcols x 128 K
            int c = tid >> 2, q = tid & 3;
            const ushort* wp = W1t + (size_t)(ch * 128 + c) * HH + q * 32;
#pragma unroll
            for (int j4 = 0; j4 < 4; ++j4)
                *(f16x8*)&Wb[c][q * 32 + j4 * 8] = *(const f16x8*)(wp + j4 * 8);
        }
        __syncthreads();
        f32x4 acc[8] = {};
#pragma unroll
        for (int k0 = 0; k0 < 128; k0 += 32) {
            f16x8 af = *(const f16x8*)&As[w * 16 + lr][k0 + lg * 8];
#pragma unroll
            for (int fc = 0; fc < 8; ++fc) {
                f16x8 bf = *(const f16x8*)&Wb[fc * 16 + lr][k0 + lg * 8];
                acc[fc] = __builtin_amdgcn_mfma_f32_16x16x32_f16(af, bf, acc[fc], 0, 0, 0);
            }
        }
#pragma unroll
        for (int fc = 0; fc < 8; ++fc) {
#pragma unroll
            for (int reg = 0; reg < 4; ++reg) {
                int rl = w * 16 + lg * 4 + reg;
                int col = ch * 128 + fc * 16 + lr;
                float val = acc[fc][reg] * 16.f + b1[col];
                float y = (val - m1[col]) * (g1v[col] * rsqrtf(v1[col] + 1e-5f)) + be1[col];
                zs[rl][col] = f2h(fmaxf(y, 0.f) * 0.0625f);
            }
        }
    }
    __syncthreads();

    // ---- phase B: h' = z@W2*16 + b2; write global + As (h'/16 fp16) ----
    ushort(*Wb2)[264] = (ushort(*)[264]) & Wb[0][0];   // 64x264 view
    for (int ch = 0; ch < 2; ++ch) {
        __syncthreads();
        {   // stage W2 half: 64 outcols x 256 K
            int c = tid >> 3, q = tid & 7;
            const ushort* wp = W2t + (size_t)(ch * 64 + c) * 256 + q * 32;
#pragma unroll
            for (int j4 = 0; j4 < 4; ++j4)
                *(f16x8*)&Wb2[c][q * 32 + j4 * 8] = *(const f16x8*)(wp + j4 * 8);
        }
        __syncthreads();
        f32x4 acc[4] = {};
#pragma unroll
        for (int k0 = 0; k0 < 256; k0 += 32) {
            f16x8 af = *(const f16x8*)&zs[w * 16 + lr][k0 + lg * 8];
#pragma unroll
            for (int fc = 0; fc < 4; ++fc) {
                f16x8 bf = *(const f16x8*)&Wb2[fc * 16 + lr][k0 + lg * 8];
                acc[fc] = __builtin_amdgcn_mfma_f32_16x16x32_f16(af, bf, acc[fc], 0, 0, 0);
            }
        }
#pragma unroll
        for (int fc = 0; fc < 4; ++fc) {
#pragma unroll
            for (int reg = 0; reg < 4; ++reg) {
                int rl = w * 16 + lg * 4 + reg;
                int col = ch * 64 + fc * 16 + lr;
                float hv = acc[fc][reg] * 16.f + b2[col];
                hio[(size_t)(r0 + rl) * HH + col] = hv;
                As[rl][col] = f2h(hv * 0.0625f);
            }
        }
    }
    // zs (z) dead from here; ts alias takes over.

    // ---- phase C: t = relu(bn(h'@W3*16 + vnW[batch])); pool ----
    for (int ch = 0; ch < 2; ++ch) {
        __syncthreads();
        {   // stage W3 half: 128 outcols x 128 K
            int c = tid >> 2, q = tid & 3;
            const ushort* wp = W3t + (size_t)(ch * 128 + c) * HH + q * 32;
#pragma unroll
            for (int j4 = 0; j4 < 4; ++j4)
                *(f16x8*)&Wb[c][q * 32 + j4 * 8] = *(const f16x8*)(wp + j4 * 8);
        }
        __syncthreads();
        f32x4 acc[8] = {};
#pragma unroll
        for (int k0 = 0; k0 < 128; k0 += 32) {
            f16x8 af = *(const f16x8*)&As[w * 16 + lr][k0 + lg * 8];
#pragma unroll
            for (int fc = 0; fc < 8; ++fc) {
                f16x8 bf = *(const f16x8*)&Wb[fc * 16 + lr][k0 + lg * 8];
                acc[fc] = __builtin_amdgcn_mfma_f32_16x16x32_f16(af, bf, acc[fc], 0, 0, 0);
            }
        }
#pragma unroll
        for (int fc = 0; fc < 8; ++fc) {
#pragma unroll
            for (int reg = 0; reg < 4; ++reg) {
                int rl = w * 16 + lg * 4 + reg;
                int colg = ch * 128 + fc * 16 + lr;
                int gg = batchL[rl];
                float val = acc[fc][reg] * 16.f + vnW[(size_t)gg * 256 + colg];
                float y = (val - m3[colg]) * (g3[colg] * rsqrtf(v3[colg] + 1e-5f)) + be3[colg];
                ts[rl][fc * 16 + lr] = fmaxf(y, 0.f);   // f32, no rounding
            }
        }
        __syncthreads();
        {   // segment pooling: thread -> col (0..127), row-chunk of 32
            int col = tid & 127, rs = (tid >> 7) * 32;
            float s = 0.f;
            int cur = batchL[rs];
            for (int r = rs; r < rs + 32; ++r) {
                int gg = batchL[r];
                if (gg != cur) {
                    atomicAdd(&pooled[(size_t)cur * 256 + ch * 128 + col], s);
                    s = 0.f; cur = gg;
                }
                s += ts[r][col];
            }
            atomicAdd(&pooled[(size_t)cur * 256 + ch * 128 + col], s);
        }
    }
}

// ---------------- small f32 GEMM (GEMM3a, GEMM4) ----------------
enum { E_BIAS = 0, E_BNRELU = 1 };
template <int EMODE>
__global__ void __launch_bounds__(256)
gemm_k(const void* __restrict__ Av, const float* __restrict__ B,
       const float* __restrict__ bias,
       const float* __restrict__ g_, const float* __restrict__ b_,
       const float* __restrict__ m_, const float* __restrict__ v_,
       void* __restrict__ outv, int K, int Nc) {
    __shared__ float As[64][33];
    __shared__ float Bs[32][64];
    const int tid = threadIdx.x;
    const int row0 = blockIdx.x * 64;
    const int col0 = blockIdx.y * 64;
    float acc[4][4] = {};
    const int tx = tid & 15, ty = tid >> 4;
    for (int k0 = 0; k0 < K; k0 += 32) {
#pragma unroll
        for (int p = 0; p < 2; ++p) {
            int idx = p * 256 + tid;
            {
                int r = idx >> 3, c = (idx & 7) << 2;
                size_t aoff = (size_t)(row0 + r) * K + k0 + c;
                float4 va = *(const float4*)((const float*)Av + aoff);
                As[r][c + 0] = va.x; As[r][c + 1] = va.y;
                As[r][c + 2] = va.z; As[r][c + 3] = va.w;
            }
            {
                int kr = idx >> 4, cc = (idx & 15) << 2;
                *(float4*)&Bs[kr][cc] =
                    *(const float4*)(B + (size_t)(k0 + kr) * Nc + col0 + cc);
            }
        }
        __syncthreads();
#pragma unroll
        for (int k = 0; k < 32; ++k) {
            float4 bv = *(const float4*)&Bs[k][tx << 2];
            float a0 = As[ty * 4 + 0][k];
            float a1 = As[ty * 4 + 1][k];
            float a2 = As[ty * 4 + 2][k];
            float a3 = As[ty * 4 + 3][k];
            acc[0][0] += a0 * bv.x; acc[0][1] += a0 * bv.y; acc[0][2] += a0 * bv.z; acc[0][3] += a0 * bv.w;
            acc[1][0] += a1 * bv.x; acc[1][1] += a1 * bv.y; acc[1][2] += a1 * bv.z; acc[1][3] += a1 * bv.w;
            acc[2][0] += a2 * bv.x; acc[2][1] += a2 * bv.y; acc[2][2] += a2 * bv.z; acc[2][3] += a2 * bv.w;
            acc[3][0] += a3 * bv.x; acc[3][1] += a3 * bv.y; acc[3][2] += a3 * bv.z; acc[3][3] += a3 * bv.w;
        }
        __syncthreads();
    }
#pragma unroll
    for (int j = 0; j < 4; ++j) {
        int gr = row0 + ty * 4 + j;
        float vals[4];
#pragma unroll
        for (int lx = 0; lx < 4; ++lx) {
            int gc = col0 + (tx << 2) + lx;
            float val = acc[j][lx];
            if (EMODE == E_BIAS) {
                vals[lx] = val + bias[gc];
            } else {
                float y = val + bias[gc];
                float s = g_[gc] * rsqrtf(v_[gc] + 1e-5f);
                y = (y - m_[gc]) * s + b_[gc];
                vals[lx] = fmaxf(y, 0.f);
            }
        }
        *(float4*)((float*)outv + (size_t)gr * Nc + col0 + (tx << 2)) =
            make_float4(vals[0], vals[1], vals[2], vals[3]);
    }
}

// ---------------- final head ----------------
__global__ void k_final(const float* __restrict__ vn, const float* __restrict__ pW1,
                        const float* __restrict__ pb1, const float* __restrict__ pW2,
                        const float* __restrict__ pb2, float* __restrict__ out) {
    int g = blockIdx.x;
    int j = threadIdx.x;
    __shared__ float vrow[HH];
    __shared__ float red[HH];
    vrow[j] = vn[(size_t)g * HH + j];
    __syncthreads();
    float acc = pb1[j];
    for (int k = 0; k < HH; ++k) acc = fmaf(vrow[k], pW1[k * HH + j], acc);
    red[j] = fmaxf(acc, 0.f) * pW2[j];
    __syncthreads();
    for (int s = 64; s > 0; s >>= 1) {
        if (j < s) red[j] += red[j + s];
        __syncthreads();
    }
    if (j == 0) out[g] = fminf(fmaxf(red[0] + pb2[0], 0.f), 50.f);
}

extern "C" void kernel_launch(void* const* d_in, const int* in_sizes, int n_in,
                              void* d_out, int out_size, void* d_ws, size_t ws_size,
                              hipStream_t stream) {
    const int*   x        = (const int*)  d_in[0];
    const int*   ei       = (const int*)  d_in[1];
    const int*   ea       = (const int*)  d_in[2];
    const int*   batch    = (const int*)  d_in[3];
    const float* atom_emb = (const float*)d_in[4];
    const float* vn_emb   = (const float*)d_in[5];
    const float* bond_emb = (const float*)d_in[6];
    const float* conv_eps = (const float*)d_in[7];
    const float* conv_W1  = (const float*)d_in[8];
    const float* conv_b1  = (const float*)d_in[9];
    const float* cbn_g    = (const float*)d_in[10];
    const float* cbn_b    = (const float*)d_in[11];
    const float* cbn_m    = (const float*)d_in[12];
    const float* cbn_v    = (const float*)d_in[13];
    const float* conv_W2  = (const float*)d_in[14];
    const float* conv_b2  = (const float*)d_in[15];
    const float* vn1_W    = (const float*)d_in[16];
    const float* vn1_b    = (const float*)d_in[17];
    const float* vn1_g    = (const float*)d_in[18];
    const float* vn1_be   = (const float*)d_in[19];
    const float* vn1_m    = (const float*)d_in[20];
    const float* vn1_v    = (const float*)d_in[21];
    const float* vn2_W    = (const float*)d_in[22];
    const float* vn2_b    = (const float*)d_in[23];
    const float* vn2_g    = (const float*)d_in[24];
    const float* vn2_be   = (const float*)d_in[25];
    const float* vn2_m    = (const float*)d_in[26];
    const float* vn2_v    = (const float*)d_in[27];
    const float* pW1      = (const float*)d_in[28];
    const float* pb1      = (const float*)d_in[29];
    const float* pW2      = (const float*)d_in[30];
    const float* pb2      = (const float*)d_in[31];

    // ---- workspace layout (~229 MB) ----
    char* base = (char*)d_ws;
    float*    h      = (float*)base;                                  // NN*HH f32
    ushort*   agg    = (ushort*)(base + (size_t)NN * HH * 4);         // NN*HH fp16
    unsigned* packed = (unsigned*)(agg + (size_t)NN * HH);            // EE u32
    int*      rowptr = (int*)(packed + EE);                           // NN+4
    int*      fill   = rowptr + NN + 4;                               // NN
    float*    ctab   = (float*)(fill + NN);                           // 512*HH f32
    int*      sums   = (int*)(ctab + 512 * HH);                       // 256
    ushort*   W1t    = (ushort*)(sums + 256);                         // 256*128
    ushort*   W2t    = W1t + 256 * 128;                               // 128*256
    ushort*   W3t    = W2t + 128 * 256;                               // 256*128
    float*    vn     = (float*)(W3t + 256 * 128);                     // GG*HH
    float*    vnW    = vn + (size_t)GG * HH;                          // GG*256
    float*    pooled = vnW + (size_t)GG * 256;                        // GG*256
    float*    out    = (float*)d_out;

    // ---- setup ----
    k_zero<<<256, 256, 0, stream>>>((float*)fill);
    k_hist<<<EE / 256, 256, 0, stream>>>(ei, fill);
    k_scan1<<<256, 256, 0, stream>>>(fill, rowptr, sums);
    k_scan2<<<1, 256, 0, stream>>>(sums);
    k_scan3<<<256, 256, 0, stream>>>(rowptr, sums, fill);
    k_scatter<<<EE / 256, 256, 0, stream>>>(ei, ea, fill, packed);
    k_atom<<<NN * 32 / 256, 256, 0, stream>>>(x, atom_emb, h);
    k_init_vn<<<GG * HH / 4 / 256, 256, 0, stream>>>(vn_emb, vn);

    for (int i = 0; i < 4; ++i) {
        k_ctab<<<64, 256, 0, stream>>>(bond_emb + (size_t)i * FBc * VBc * HH, ctab);
        k_agg<<<NN / 4, 256, 0, stream>>>(h, vn, batch, rowptr, packed, ctab, agg);
        k_wt<<<128, 256, 0, stream>>>(conv_W1 + (size_t)i * HH * 256, W1t, 7, 256);
        k_wt<<<128, 256, 0, stream>>>(conv_W2 + (size_t)i * 256 * HH, W2t, 8, 128);
        k_wt<<<128, 256, 0, stream>>>(vn1_W + (size_t)i * 256 * 256 + 128 * 256, W3t, 7, 256);

        // GEMM3a: vnW = vn @ vn1_W[:128] + vn1_b   (needed by k_conv phase C)
        {
            dim3 g3(GG / 64, 4);
            gemm_k<E_BIAS><<<g3, 256, 0, stream>>>(
                vn, vn1_W + (size_t)i * 256 * 256, vn1_b + i * 256,
                nullptr, nullptr, nullptr, nullptr, vnW, HH, 256);
        }
        k_zero<<<GG * 256 / 4 / 256, 256, 0, stream>>>(pooled);

        // mega-kernel: conv MLP + vn1-bottom + pool
        k_conv<<<NN / 128, 512, 0, stream>>>(
            h, agg, W1t, W2t, W3t, batch, vn, vnW, conv_eps + i,
            conv_b1 + i * 256, cbn_g + i * 256, cbn_b + i * 256,
            cbn_m + i * 256, cbn_v + i * 256, conv_b2 + i * HH,
            vn1_g + i * 256, vn1_be + i * 256, vn1_m + i * 256, vn1_v + i * 256,
            pooled);

        // GEMM4: vn = relu(bn(pooled @ vn2_W + vn2_b))
        {
            dim3 g4(GG / 64, 2);
            gemm_k<E_BNRELU><<<g4, 256, 0, stream>>>(
                pooled, vn2_W + (size_t)i * 256 * HH, vn2_b + i * HH,
                vn2_g + i * HH, vn2_be + i * HH, vn2_m + i * HH, vn2_v + i * HH,
                vn, 256, HH);
        }
    }
    k_final<<<GG, 128, 0, stream>>>(vn, pW1, pb1, pW2, pb2, out);
}

// Round 10
// 1702.723 us; speedup vs baseline: 8.7727x; 1.0663x over previous
//
#include <hip/hip_runtime.h>
#include <hip/hip_fp16.h>

#define NN 262144
#define EE 1048576
#define GG 8192
#define HH 128
#define FBc 3
#define VAc 64
#define VBc 8
#define FAc 9

typedef _Float16 f16;
typedef _Float16 f16x8 __attribute__((ext_vector_type(8)));
typedef float f32x4 __attribute__((ext_vector_type(4)));

__device__ __forceinline__ float h2f(ushort u) {
    __half h; *(ushort*)&h = u; return __half2float(h);
}
__device__ __forceinline__ ushort f2h(float f) {
    __half h = __float2half_rn(f); return *(ushort*)&h;
}

// ---------------- zero fill ----------------
__global__ void k_zero(float* __restrict__ p) {
    size_t i = (size_t)(blockIdx.x * 256 + threadIdx.x) * 4;
    *(float4*)(p + i) = make_float4(0.f, 0.f, 0.f, 0.f);
}

// ---------------- atom encoder: h16 = (sum emb)/16 fp16 ----------------
__global__ void k_atom(const int* __restrict__ x, const float* __restrict__ emb,
                       ushort* __restrict__ h16) {
    int t = blockIdx.x * 256 + threadIdx.x;
    int n = t >> 5, c = (t & 31) << 2;
    if (n >= NN) return;
    float4 a = make_float4(0.f, 0.f, 0.f, 0.f);
#pragma unroll
    for (int f = 0; f < FAc; ++f) {
        int v = x[n * FAc + f];
        float4 e = *(const float4*)(emb + ((size_t)(f * VAc + v)) * HH + c);
        a.x += e.x; a.y += e.y; a.z += e.z; a.w += e.w;
    }
    ushort4 o;
    o.x = f2h(a.x * 0.0625f); o.y = f2h(a.y * 0.0625f);
    o.z = f2h(a.z * 0.0625f); o.w = f2h(a.w * 0.0625f);
    *(ushort4*)(h16 + (size_t)n * HH + c) = o;
}

// ---------------- vn init ----------------
__global__ void k_init_vn(const float* __restrict__ vn_emb, float* __restrict__ vn) {
    int t = blockIdx.x * 256 + threadIdx.x;
    int g = t >> 5, c = (t & 31) << 2;
    *(float4*)(vn + (size_t)g * HH + c) = *(const float4*)(vn_emb + c);
}

// ================= CSR build =================
__global__ void k_hist(const int* __restrict__ ei, int* __restrict__ deg) {
    int e = blockIdx.x * 256 + threadIdx.x;
    atomicAdd(&deg[ei[EE + e]], 1);
}
__global__ void k_scan1(const int* __restrict__ deg, int* __restrict__ rowptr,
                        int* __restrict__ sums) {
    __shared__ int s[256];
    int base = blockIdx.x * 1024 + threadIdx.x * 4;
    int4 d = *(const int4*)(deg + base);
    int t = d.x + d.y + d.z + d.w;
    s[threadIdx.x] = t;
    __syncthreads();
    for (int off = 1; off < 256; off <<= 1) {
        int v = (threadIdx.x >= off) ? s[threadIdx.x - off] : 0;
        __syncthreads();
        s[threadIdx.x] += v;
        __syncthreads();
    }
    int excl = s[threadIdx.x] - t;
    int4 o; o.x = excl; o.y = excl + d.x; o.z = o.y + d.y; o.w = o.z + d.z;
    *(int4*)(rowptr + base) = o;
    if (threadIdx.x == 255) sums[blockIdx.x] = s[255];
}
__global__ void k_scan2(int* __restrict__ sums) {
    __shared__ int s[256];
    int t = sums[threadIdx.x];
    s[threadIdx.x] = t;
    __syncthreads();
    for (int off = 1; off < 256; off <<= 1) {
        int v = (threadIdx.x >= off) ? s[threadIdx.x - off] : 0;
        __syncthreads();
        s[threadIdx.x] += v;
        __syncthreads();
    }
    sums[threadIdx.x] = s[threadIdx.x] - t;
}
__global__ void k_scan3(int* __restrict__ rowptr, const int* __restrict__ sums,
                        int* __restrict__ fill) {
    int base = blockIdx.x * 1024 + threadIdx.x * 4;
    int add = sums[blockIdx.x];
    int4 r = *(const int4*)(rowptr + base);
    r.x += add; r.y += add; r.z += add; r.w += add;
    *(int4*)(rowptr + base) = r;
    *(int4*)(fill + base) = r;
    if (blockIdx.x == 0 && threadIdx.x == 0) rowptr[NN] = EE;
}
__global__ void k_scatter(const int* __restrict__ ei, const int* __restrict__ ea,
                          int* __restrict__ fill, unsigned* __restrict__ packed) {
    int e = blockIdx.x * 256 + threadIdx.x;
    int dst = ei[EE + e];
    int pos = atomicAdd(&fill[dst], 1);
    unsigned cb = (unsigned)(ea[e * 3 + 0] + ea[e * 3 + 1] * 8 + ea[e * 3 + 2] * 64);
    packed[pos] = (unsigned)ei[e] | (cb << 18);
}

// per-layer bond-combo table
__global__ void k_ctab(const float* __restrict__ bemb, float* __restrict__ ctab) {
    int t = blockIdx.x * 256 + threadIdx.x;
    int cb = t >> 5, c = (t & 31) << 2;
    int a0 = cb & 7, a1 = (cb >> 3) & 7, a2 = cb >> 6;
    float4 b0 = *(const float4*)(bemb + (size_t)(0 * VBc + a0) * HH + c);
    float4 b1 = *(const float4*)(bemb + (size_t)(1 * VBc + a1) * HH + c);
    float4 b2 = *(const float4*)(bemb + (size_t)(2 * VBc + a2) * HH + c);
    float4 o = make_float4(b0.x + b1.x + b2.x, b0.y + b1.y + b2.y,
                           b0.z + b1.z + b2.z, b0.w + b1.w + b2.w);
    *(float4*)(ctab + (size_t)cb * HH + c) = o;
}

// per-layer folded BN tables
__global__ void k_prep(const float* __restrict__ b1, const float* __restrict__ g1,
                       const float* __restrict__ be1, const float* __restrict__ m1,
                       const float* __restrict__ v1,
                       const float* __restrict__ g3, const float* __restrict__ be3,
                       const float* __restrict__ m3, const float* __restrict__ v3,
                       float* __restrict__ ZA, float* __restrict__ ZB,
                       float* __restrict__ TA, float* __restrict__ TB,
                       float* __restrict__ S3) {
    int c = threadIdx.x;   // 256
    float s1 = g1[c] * rsqrtf(v1[c] + 1e-5f);
    ZA[c] = s1;
    ZB[c] = ((b1[c] - m1[c]) * s1 + be1[c]) * 0.0625f;
    float s3 = g3[c] * rsqrtf(v3[c] + 1e-5f);
    TA[c] = 16.f * s3;
    TB[c] = be3[c] - m3[c] * s3;
    S3[c] = s3;
}

// weight transpose: W [K][Nsrc] f32 -> Wt [N][K] fp16
__global__ void k_wt(const float* __restrict__ W, ushort* __restrict__ Wt, int lk, int Nsrc) {
    int o = blockIdx.x * 256 + threadIdx.x;
    int K = 1 << lk;
    int c = o >> lk, k = o & (K - 1);
    Wt[o] = f2h(W[(size_t)k * Nsrc + c]);
}

// CSR aggregation (h16 gather): agg[n] = (1/16) sum relu(16*h16[src]+vn[batch[src]]+ctab)
__global__ void k_agg(const ushort* __restrict__ h16, const float* __restrict__ vn,
                      const int* __restrict__ batch,
                      const int* __restrict__ rowptr, const unsigned* __restrict__ packed,
                      const float* __restrict__ ctab, ushort* __restrict__ agg) {
    int n = blockIdx.x * 4 + (threadIdx.x >> 6);
    int lane = threadIdx.x & 63;
    int co = lane * 2;
    int beg = rowptr[n], end = rowptr[n + 1];
    float a0 = 0.f, a1 = 0.f;
    int i = beg;
    for (; i + 1 < end; i += 2) {
        unsigned p0 = packed[i], p1 = packed[i + 1];
        int s0 = p0 & 0x3FFFF, s1 = p1 & 0x3FFFF;
        int c0 = p0 >> 18, c1 = p1 >> 18;
        ushort2 u0 = *(const ushort2*)(h16 + (size_t)s0 * HH + co);
        ushort2 u1 = *(const ushort2*)(h16 + (size_t)s1 * HH + co);
        float2 v0 = *(const float2*)(vn + (size_t)batch[s0] * HH + co);
        float2 v1 = *(const float2*)(vn + (size_t)batch[s1] * HH + co);
        float2 t0 = *(const float2*)(ctab + (size_t)c0 * HH + co);
        float2 t1 = *(const float2*)(ctab + (size_t)c1 * HH + co);
        a0 += fmaxf(16.f * h2f(u0.x) + v0.x + t0.x, 0.f)
            + fmaxf(16.f * h2f(u1.x) + v1.x + t1.x, 0.f);
        a1 += fmaxf(16.f * h2f(u0.y) + v0.y + t0.y, 0.f)
            + fmaxf(16.f * h2f(u1.y) + v1.y + t1.y, 0.f);
    }
    if (i < end) {
        unsigned p = packed[i];
        int src = p & 0x3FFFF, cb = p >> 18;
        ushort2 u = *(const ushort2*)(h16 + (size_t)src * HH + co);
        float2 vv = *(const float2*)(vn + (size_t)batch[src] * HH + co);
        float2 ct = *(const float2*)(ctab + (size_t)cb * HH + co);
        a0 += fmaxf(16.f * h2f(u.x) + vv.x + ct.x, 0.f);
        a1 += fmaxf(16.f * h2f(u.y) + vv.y + ct.y, 0.f);
    }
    ushort2 o; o.x = f2h(a0 * 0.0625f); o.y = f2h(a1 * 0.0625f);
    *(ushort2*)(agg + (size_t)n * HH + co) = o;
}

// ============== mega-kernel: conv MLP + vn1-bottom + segment pool ==============
// All LDS tiles XOR-swizzled at 16B-block granularity: blk ^= (row & 7).
// Wave-local row ownership (wave w owns rows w*16..w*16+15) -> barriers only
// around shared weight tiles + pool.
__global__ void __launch_bounds__(512)
k_conv(ushort* __restrict__ h16, const ushort* __restrict__ agg,
       const ushort* __restrict__ W1t, const ushort* __restrict__ W2t,
       const ushort* __restrict__ W3t,
       const int* __restrict__ batch, const float* __restrict__ vn,
       const float* __restrict__ vnW,
       const float* __restrict__ eps_ptr,
       const float* __restrict__ ZA, const float* __restrict__ ZB,
       const float* __restrict__ b2,
       const float* __restrict__ TA, const float* __restrict__ TB,
       float* __restrict__ pooled) {
    __shared__ ushort As[128][128];   // A/16, then h'/16        32 KB
    __shared__ ushort zs[128][256];   // z/16, then t (unscaled)  64 KB
    __shared__ ushort Wb[128][128];   // weight tiles             32 KB
    __shared__ int batchL[128];
    const int tid = threadIdx.x;
    const int r0 = blockIdx.x * 128;
    const int w = tid >> 6, l = tid & 63, lr = l & 15, lg = l >> 4, lr7 = lr & 7;
    if (tid < 128) batchL[tid] = batch[r0 + tid];
    const float eps1 = 1.f + eps_ptr[0];

    // ---- stage A (wave-local): A/16 = eps1*(h16 + vn/16) + agg16 ----
    {
        int row = w * 16 + (l >> 2), q = l & 3, r7 = row & 7;
        int gg = batch[r0 + row];
        const ushort* hp = h16 + (size_t)(r0 + row) * HH;
        const float* vp = vn + (size_t)gg * HH;
        const ushort* ap = agg + (size_t)(r0 + row) * HH;
#pragma unroll
        for (int j4 = 0; j4 < 4; ++j4) {
            int c0 = q * 32 + j4 * 8;
            f16x8 hv = *(const f16x8*)(hp + c0);
            float4 v0 = *(const float4*)(vp + c0);
            float4 v1 = *(const float4*)(vp + c0 + 4);
            f16x8 ag = *(const f16x8*)(ap + c0);
            float vv[8] = {v0.x, v0.y, v0.z, v0.w, v1.x, v1.y, v1.z, v1.w};
            f16x8 o;
#pragma unroll
            for (int j = 0; j < 8; ++j)
                o[j] = (f16)(eps1 * ((float)hv[j] + vv[j] * 0.0625f) + (float)ag[j]);
            *(f16x8*)&As[row][((c0 >> 3) ^ r7) << 3] = o;
        }
    }

    f32x4 acc[8];
    // ---- phase A: z = relu(acc*ZA + ZB), stored /16 in zs ----
    for (int ch = 0; ch < 2; ++ch) {
        if (ch) __syncthreads();
        {   // stage W1 half [128][128]
            int c = tid >> 2, q = tid & 3, c7 = c & 7;
#pragma unroll
            for (int j4 = 0; j4 < 4; ++j4) {
                int blk = q * 4 + j4;
                *(f16x8*)&Wb[c][(blk ^ c7) << 3] =
                    *(const f16x8*)(W1t + (size_t)(ch * 128 + c) * 128 + blk * 8);
            }
        }
        __syncthreads();
#pragma unroll
        for (int fc = 0; fc < 8; ++fc) acc[fc] = (f32x4){0.f, 0.f, 0.f, 0.f};
#pragma unroll
        for (int k0 = 0; k0 < 4; ++k0) {
            int sb = ((k0 * 4 + lg) ^ lr7) << 3;
            f16x8 af = *(const f16x8*)&As[w * 16 + lr][sb];
#pragma unroll
            for (int fc = 0; fc < 8; ++fc) {
                f16x8 bf = *(const f16x8*)&Wb[fc * 16 + lr][sb];
                acc[fc] = __builtin_amdgcn_mfma_f32_16x16x32_f16(af, bf, acc[fc], 0, 0, 0);
            }
        }
#pragma unroll
        for (int fc = 0; fc < 8; ++fc) {
            int col = ch * 128 + fc * 16 + lr;
            float za = ZA[col], zb = ZB[col];
#pragma unroll
            for (int reg = 0; reg < 4; ++reg) {
                int rl = w * 16 + lg * 4 + reg;
                float zv = fmaxf(acc[fc][reg] * za + zb, 0.f);
                ((ushort*)zs)[rl * 256 + ((((col >> 3) ^ (rl & 7)) << 3) | (col & 7))] = f2h(zv);
            }
        }
    }

    // ---- phase B: h' = acc*16 + b2 -> global h16 + As ----
    for (int ch2 = 0; ch2 < 2; ++ch2) {
        __syncthreads();
        {   // stage W2 half [64][256] into Wb (flattened)
            int c = tid >> 3, q = tid & 7, c7 = c & 7;
#pragma unroll
            for (int j4 = 0; j4 < 4; ++j4) {
                int blk = q * 4 + j4;
                *(f16x8*)((ushort*)Wb + c * 256 + ((blk ^ c7) << 3)) =
                    *(const f16x8*)(W2t + (size_t)(ch2 * 64 + c) * 256 + blk * 8);
            }
        }
        __syncthreads();
#pragma unroll
        for (int fc = 0; fc < 4; ++fc) acc[fc] = (f32x4){0.f, 0.f, 0.f, 0.f};
#pragma unroll
        for (int k0 = 0; k0 < 8; ++k0) {
            int sb = ((k0 * 4 + lg) ^ lr7) << 3;
            f16x8 af = *(const f16x8*)&zs[w * 16 + lr][sb];
#pragma unroll
            for (int fc = 0; fc < 4; ++fc) {
                f16x8 bf = *(const f16x8*)((ushort*)Wb + (fc * 16 + lr) * 256 + sb);
                acc[fc] = __builtin_amdgcn_mfma_f32_16x16x32_f16(af, bf, acc[fc], 0, 0, 0);
            }
        }
#pragma unroll
        for (int fc = 0; fc < 4; ++fc) {
            int col = ch2 * 64 + fc * 16 + lr;
            float bb = b2[col];
#pragma unroll
            for (int reg = 0; reg < 4; ++reg) {
                int rl = w * 16 + lg * 4 + reg;
                float hv = acc[fc][reg] * 16.f + bb;
                ushort hq = f2h(hv * 0.0625f);
                h16[(size_t)(r0 + rl) * HH + col] = hq;
                As[rl][(((col >> 3) ^ (rl & 7)) << 3) | (col & 7)] = hq;
            }
        }
    }

    // ---- phase C: t = relu(acc*TA + vnW' + TB) -> zs (unscaled fp16) ----
    for (int ch3 = 0; ch3 < 2; ++ch3) {
        __syncthreads();
        {   // stage W3 half [128][128]
            int c = tid >> 2, q = tid & 3, c7 = c & 7;
#pragma unroll
            for (int j4 = 0; j4 < 4; ++j4) {
                int blk = q * 4 + j4;
                *(f16x8*)&Wb[c][(blk ^ c7) << 3] =
                    *(const f16x8*)(W3t + (size_t)(ch3 * 128 + c) * 128 + blk * 8);
            }
        }
        __syncthreads();
#pragma unroll
        for (int fc = 0; fc < 8; ++fc) acc[fc] = (f32x4){0.f, 0.f, 0.f, 0.f};
#pragma unroll
        for (int k0 = 0; k0 < 4; ++k0) {
            int sb = ((k0 * 4 + lg) ^ lr7) << 3;
            f16x8 af = *(const f16x8*)&As[w * 16 + lr][sb];
#pragma unroll
            for (int fc = 0; fc < 8; ++fc) {
                f16x8 bf = *(const f16x8*)&Wb[fc * 16 + lr][sb];
                acc[fc] = __builtin_amdgcn_mfma_f32_16x16x32_f16(af, bf, acc[fc], 0, 0, 0);
            }
        }
        const float* vp[4];
        int rls[4];
#pragma unroll
        for (int reg = 0; reg < 4; ++reg) {
            rls[reg] = w * 16 + lg * 4 + reg;
            vp[reg] = vnW + (size_t)batchL[rls[reg]] * 256;
        }
#pragma unroll
        for (int fc = 0; fc < 8; ++fc) {
            int colg = ch3 * 128 + fc * 16 + lr;
            float ta = TA[colg], tb = TB[colg];
#pragma unroll
            for (int reg = 0; reg < 4; ++reg) {
                int rl = rls[reg];
                float tv = fmaxf(acc[fc][reg] * ta + vp[reg][colg] + tb, 0.f);
                ((ushort*)zs)[rl * 256 + ((((colg >> 3) ^ (rl & 7)) << 3) | (colg & 7))] = f2h(tv);
            }
        }
    }
    __syncthreads();
    // ---- pool: run-length segment sum over sorted batch ----
    {
        int col = tid & 255, rs = (tid >> 8) * 64;
        float s = 0.f;
        int cur = batchL[rs];
        for (int r = rs; r < rs + 64; ++r) {
            int gg = batchL[r];
            if (gg != cur) {
                atomicAdd(&pooled[(size_t)cur * 256 + col], s);
                s = 0.f; cur = gg;
            }
            s += h2f(((const ushort*)zs)[r * 256 + ((((col >> 3) ^ (r & 7)) << 3) | (col & 7))]);
        }
        atomicAdd(&pooled[(size_t)cur * 256 + col], s);
    }
}

// ---------------- small f32 GEMM (GEMM3a, GEMM4) ----------------
enum { E_BIAS = 0, E_BNRELU = 1 };
template <int EMODE>
__global__ void __launch_bounds__(256)
gemm_k(const void* __restrict__ Av, const float* __restrict__ B,
       const float* __restrict__ bias,
       const float* __restrict__ g_, const float* __restrict__ b_,
       const float* __restrict__ m_, const float* __restrict__ v_,
       const float* __restrict__ scp,
       void* __restrict__ outv, int K, int Nc) {
    __shared__ float As[64][33];
    __shared__ float Bs[32][64];
    const int tid = threadIdx.x;
    const int row0 = blockIdx.x * 64;
    const int col0 = blockIdx.y * 64;
    float acc[4][4] = {};
    const int tx = tid & 15, ty = tid >> 4;
    for (int k0 = 0; k0 < K; k0 += 32) {
#pragma unroll
        for (int p = 0; p < 2; ++p) {
            int idx = p * 256 + tid;
            {
                int r = idx >> 3, c = (idx & 7) << 2;
                size_t aoff = (size_t)(row0 + r) * K + k0 + c;
                float4 va = *(const float4*)((const float*)Av + aoff);
                As[r][c + 0] = va.x; As[r][c + 1] = va.y;
                As[r][c + 2] = va.z; As[r][c + 3] = va.w;
            }
            {
                int kr = idx >> 4, cc = (idx & 15) << 2;
                *(float4*)&Bs[kr][cc] =
                    *(const float4*)(B + (size_t)(k0 + kr) * Nc + col0 + cc);
            }
        }
        __syncthreads();
#pragma unroll
        for (int k = 0; k < 32; ++k) {
            float4 bv = *(const float4*)&Bs[k][tx << 2];
            float a0 = As[ty * 4 + 0][k];
            float a1 = As[ty * 4 + 1][k];
            float a2 = As[ty * 4 + 2][k];
            float a3 = As[ty * 4 + 3][k];
            acc[0][0] += a0 * bv.x; acc[0][1] += a0 * bv.y; acc[0][2] += a0 * bv.z; acc[0][3] += a0 * bv.w;
            acc[1][0] += a1 * bv.x; acc[1][1] += a1 * bv.y; acc[1][2] += a1 * bv.z; acc[1][3] += a1 * bv.w;
            acc[2][0] += a2 * bv.x; acc[2][1] += a2 * bv.y; acc[2][2] += a2 * bv.z; acc[2][3] += a2 * bv.w;
            acc[3][0] += a3 * bv.x; acc[3][1] += a3 * bv.y; acc[3][2] += a3 * bv.z; acc[3][3] += a3 * bv.w;
        }
        __syncthreads();
    }
#pragma unroll
    for (int j = 0; j < 4; ++j) {
        int gr = row0 + ty * 4 + j;
        float vals[4];
#pragma unroll
        for (int lx = 0; lx < 4; ++lx) {
            int gc = col0 + (tx << 2) + lx;
            float val = acc[j][lx];
            if (EMODE == E_BIAS) {
                float v = val + bias[gc];
                if (scp) v *= scp[gc];
                vals[lx] = v;
            } else {
                float y = val + bias[gc];
                float s = g_[gc] * rsqrtf(v_[gc] + 1e-5f);
                y = (y - m_[gc]) * s + b_[gc];
                vals[lx] = fmaxf(y, 0.f);
            }
        }
        *(float4*)((float*)outv + (size_t)gr * Nc + col0 + (tx << 2)) =
            make_float4(vals[0], vals[1], vals[2], vals[3]);
    }
}

// ---------------- final head ----------------
__global__ void k_final(const float* __restrict__ vn, const float* __restrict__ pW1,
                        const float* __restrict__ pb1, const float* __restrict__ pW2,
                        const float* __restrict__ pb2, float* __restrict__ out) {
    int g = blockIdx.x;
    int j = threadIdx.x;
    __shared__ float vrow[HH];
    __shared__ float red[HH];
    vrow[j] = vn[(size_t)g * HH + j];
    __syncthreads();
    float acc = pb1[j];
    for (int k = 0; k < HH; ++k) acc = fmaf(vrow[k], pW1[k * HH + j], acc);
    red[j] = fmaxf(acc, 0.f) * pW2[j];
    __syncthreads();
    for (int s = 64; s > 0; s >>= 1) {
        if (j < s) red[j] += red[j + s];
        __syncthreads();
    }
    if (j == 0) out[g] = fminf(fmaxf(red[0] + pb2[0], 0.f), 50.f);
}

extern "C" void kernel_launch(void* const* d_in, const int* in_sizes, int n_in,
                              void* d_out, int out_size, void* d_ws, size_t ws_size,
                              hipStream_t stream) {
    const int*   x        = (const int*)  d_in[0];
    const int*   ei       = (const int*)  d_in[1];
    const int*   ea       = (const int*)  d_in[2];
    const int*   batch    = (const int*)  d_in[3];
    const float* atom_emb = (const float*)d_in[4];
    const float* vn_emb   = (const float*)d_in[5];
    const float* bond_emb = (const float*)d_in[6];
    const float* conv_eps = (const float*)d_in[7];
    const float* conv_W1  = (const float*)d_in[8];
    const float* conv_b1  = (const float*)d_in[9];
    const float* cbn_g    = (const float*)d_in[10];
    const float* cbn_b    = (const float*)d_in[11];
    const float* cbn_m    = (const float*)d_in[12];
    const float* cbn_v    = (const float*)d_in[13];
    const float* conv_W2  = (const float*)d_in[14];
    const float* conv_b2  = (const float*)d_in[15];
    const float* vn1_W    = (const float*)d_in[16];
    const float* vn1_b    = (const float*)d_in[17];
    const float* vn1_g    = (const float*)d_in[18];
    const float* vn1_be   = (const float*)d_in[19];
    const float* vn1_m    = (const float*)d_in[20];
    const float* vn1_v    = (const float*)d_in[21];
    const float* vn2_W    = (const float*)d_in[22];
    const float* vn2_b    = (const float*)d_in[23];
    const float* vn2_g    = (const float*)d_in[24];
    const float* vn2_be   = (const float*)d_in[25];
    const float* vn2_m    = (const float*)d_in[26];
    const float* vn2_v    = (const float*)d_in[27];
    const float* pW1      = (const float*)d_in[28];
    const float* pb1      = (const float*)d_in[29];
    const float* pW2      = (const float*)d_in[30];
    const float* pb2      = (const float*)d_in[31];

    // ---- workspace layout (~162 MB) ----
    char* base = (char*)d_ws;
    ushort*   h16    = (ushort*)base;                                 // NN*HH fp16 (state/16)
    ushort*   agg    = h16 + (size_t)NN * HH;                         // NN*HH fp16
    unsigned* packed = (unsigned*)(agg + (size_t)NN * HH);            // EE u32
    int*      rowptr = (int*)(packed + EE);                           // NN+4
    int*      fill   = rowptr + NN + 4;                               // NN
    float*    ctab   = (float*)(fill + NN);                           // 512*HH f32
    int*      sums   = (int*)(ctab + 512 * HH);                       // 256
    ushort*   W1t    = (ushort*)(sums + 256);                         // 256*128
    ushort*   W2t    = W1t + 256 * 128;                               // 128*256
    ushort*   W3t    = W2t + 128 * 256;                               // 256*128
    float*    ZA     = (float*)(W3t + 256 * 128);                     // 256
    float*    ZB     = ZA + 256;
    float*    TA     = ZB + 256;
    float*    TB     = TA + 256;
    float*    S3     = TB + 256;
    float*    vn     = S3 + 256;                                      // GG*HH
    float*    vnW    = vn + (size_t)GG * HH;                          // GG*256
    float*    pooled = vnW + (size_t)GG * 256;                        // GG*256
    float*    out    = (float*)d_out;

    // ---- setup ----
    k_zero<<<256, 256, 0, stream>>>((float*)fill);
    k_hist<<<EE / 256, 256, 0, stream>>>(ei, fill);
    k_scan1<<<256, 256, 0, stream>>>(fill, rowptr, sums);
    k_scan2<<<1, 256, 0, stream>>>(sums);
    k_scan3<<<256, 256, 0, stream>>>(rowptr, sums, fill);
    k_scatter<<<EE / 256, 256, 0, stream>>>(ei, ea, fill, packed);
    k_atom<<<NN * 32 / 256, 256, 0, stream>>>(x, atom_emb, h16);
    k_init_vn<<<GG * HH / 4 / 256, 256, 0, stream>>>(vn_emb, vn);

    for (int i = 0; i < 4; ++i) {
        k_ctab<<<64, 256, 0, stream>>>(bond_emb + (size_t)i * FBc * VBc * HH, ctab);
        k_prep<<<1, 256, 0, stream>>>(
            conv_b1 + i * 256, cbn_g + i * 256, cbn_b + i * 256,
            cbn_m + i * 256, cbn_v + i * 256,
            vn1_g + i * 256, vn1_be + i * 256, vn1_m + i * 256, vn1_v + i * 256,
            ZA, ZB, TA, TB, S3);
        k_wt<<<128, 256, 0, stream>>>(conv_W1 + (size_t)i * HH * 256, W1t, 7, 256);
        k_wt<<<128, 256, 0, stream>>>(conv_W2 + (size_t)i * 256 * HH, W2t, 8, 128);
        k_wt<<<128, 256, 0, stream>>>(vn1_W + (size_t)i * 256 * 256 + 128 * 256, W3t, 7, 256);

        k_agg<<<NN / 4, 256, 0, stream>>>(h16, vn, batch, rowptr, packed, ctab, agg);

        // GEMM3a: vnW' = (vn @ vn1_W[:128] + vn1_b) * s3
        {
            dim3 g3(GG / 64, 4);
            gemm_k<E_BIAS><<<g3, 256, 0, stream>>>(
                vn, vn1_W + (size_t)i * 256 * 256, vn1_b + i * 256,
                nullptr, nullptr, nullptr, nullptr, S3, vnW, HH, 256);
        }
        k_zero<<<GG * 256 / 4 / 256, 256, 0, stream>>>(pooled);

        // mega-kernel
        k_conv<<<NN / 128, 512, 0, stream>>>(
            h16, agg, W1t, W2t, W3t, batch, vn, vnW, conv_eps + i,
            ZA, ZB, conv_b2 + i * HH, TA, TB, pooled);

        // GEMM4: vn = relu(bn(pooled @ vn2_W + vn2_b))
        {
            dim3 g4(GG / 64, 2);
            gemm_k<E_BNRELU><<<g4, 256, 0, stream>>>(
                pooled, vn2_W + (size_t)i * 256 * HH, vn2_b + i * HH,
                vn2_g + i * HH, vn2_be + i * HH, vn2_m + i * HH, vn2_v + i * HH,
                nullptr, vn, 256, HH);
        }
    }
    k_final<<<GG, 128, 0, stream>>>(vn, pW1, pb1, pW2, pb2, out);
}

// Round 11
// 1608.785 us; speedup vs baseline: 9.2849x; 1.0584x over previous
//
#include <hip/hip_runtime.h>
#include <hip/hip_fp16.h>

#define NN 262144
#define EE 1048576
#define GG 8192
#define HH 128
#define FBc 3
#define VAc 64
#define VBc 8
#define FAc 9

typedef _Float16 f16;
typedef _Float16 f16x8 __attribute__((ext_vector_type(8)));
typedef float f32x4 __attribute__((ext_vector_type(4)));

__device__ __forceinline__ float h2f(ushort u) {
    __half h; *(ushort*)&h = u; return __half2float(h);
}
__device__ __forceinline__ ushort f2h(float f) {
    __half h = __float2half_rn(f); return *(ushort*)&h;
}

// ---------------- zero fill ----------------
__global__ void k_zero(float* __restrict__ p) {
    size_t i = (size_t)(blockIdx.x * 256 + threadIdx.x) * 4;
    *(float4*)(p + i) = make_float4(0.f, 0.f, 0.f, 0.f);
}

// ---------------- atom encoder: h16 = (sum emb)/16 fp16 ----------------
__global__ void k_atom(const int* __restrict__ x, const float* __restrict__ emb,
                       ushort* __restrict__ h16) {
    int t = blockIdx.x * 256 + threadIdx.x;
    int n = t >> 5, c = (t & 31) << 2;
    if (n >= NN) return;
    float4 a = make_float4(0.f, 0.f, 0.f, 0.f);
#pragma unroll
    for (int f = 0; f < FAc; ++f) {
        int v = x[n * FAc + f];
        float4 e = *(const float4*)(emb + ((size_t)(f * VAc + v)) * HH + c);
        a.x += e.x; a.y += e.y; a.z += e.z; a.w += e.w;
    }
    ushort4 o;
    o.x = f2h(a.x * 0.0625f); o.y = f2h(a.y * 0.0625f);
    o.z = f2h(a.z * 0.0625f); o.w = f2h(a.w * 0.0625f);
    *(ushort4*)(h16 + (size_t)n * HH + c) = o;
}

// ---------------- vn init ----------------
__global__ void k_init_vn(const float* __restrict__ vn_emb, float* __restrict__ vn) {
    int t = blockIdx.x * 256 + threadIdx.x;
    int g = t >> 5, c = (t & 31) << 2;
    *(float4*)(vn + (size_t)g * HH + c) = *(const float4*)(vn_emb + c);
}

// ---------------- vn16 = vn/16 fp16 ----------------
__global__ void k_vn16(const float* __restrict__ vn, ushort* __restrict__ vn16) {
    int t = blockIdx.x * 256 + threadIdx.x;   // GG*HH/4 threads
    float4 v = *(const float4*)(vn + (size_t)t * 4);
    ushort4 o;
    o.x = f2h(v.x * 0.0625f); o.y = f2h(v.y * 0.0625f);
    o.z = f2h(v.z * 0.0625f); o.w = f2h(v.w * 0.0625f);
    *(ushort4*)(vn16 + (size_t)t * 4) = o;
}

// ================= CSR build =================
__global__ void k_hist(const int* __restrict__ ei, int* __restrict__ deg) {
    int e = blockIdx.x * 256 + threadIdx.x;
    atomicAdd(&deg[ei[EE + e]], 1);
}
__global__ void k_scan1(const int* __restrict__ deg, int* __restrict__ rowptr,
                        int* __restrict__ sums) {
    __shared__ int s[256];
    int base = blockIdx.x * 1024 + threadIdx.x * 4;
    int4 d = *(const int4*)(deg + base);
    int t = d.x + d.y + d.z + d.w;
    s[threadIdx.x] = t;
    __syncthreads();
    for (int off = 1; off < 256; off <<= 1) {
        int v = (threadIdx.x >= off) ? s[threadIdx.x - off] : 0;
        __syncthreads();
        s[threadIdx.x] += v;
        __syncthreads();
    }
    int excl = s[threadIdx.x] - t;
    int4 o; o.x = excl; o.y = excl + d.x; o.z = o.y + d.y; o.w = o.z + d.z;
    *(int4*)(rowptr + base) = o;
    if (threadIdx.x == 255) sums[blockIdx.x] = s[255];
}
__global__ void k_scan2(int* __restrict__ sums) {
    __shared__ int s[256];
    int t = sums[threadIdx.x];
    s[threadIdx.x] = t;
    __syncthreads();
    for (int off = 1; off < 256; off <<= 1) {
        int v = (threadIdx.x >= off) ? s[threadIdx.x - off] : 0;
        __syncthreads();
        s[threadIdx.x] += v;
        __syncthreads();
    }
    sums[threadIdx.x] = s[threadIdx.x] - t;
}
__global__ void k_scan3(int* __restrict__ rowptr, const int* __restrict__ sums,
                        int* __restrict__ fill) {
    int base = blockIdx.x * 1024 + threadIdx.x * 4;
    int add = sums[blockIdx.x];
    int4 r = *(const int4*)(rowptr + base);
    r.x += add; r.y += add; r.z += add; r.w += add;
    *(int4*)(rowptr + base) = r;
    *(int4*)(fill + base) = r;
    if (blockIdx.x == 0 && threadIdx.x == 0) rowptr[NN] = EE;
}
__global__ void k_scatter(const int* __restrict__ ei, const int* __restrict__ ea,
                          int* __restrict__ fill, unsigned* __restrict__ packed) {
    int e = blockIdx.x * 256 + threadIdx.x;
    int dst = ei[EE + e];
    int pos = atomicAdd(&fill[dst], 1);
    unsigned cb = (unsigned)(ea[e * 3 + 0] + ea[e * 3 + 1] * 8 + ea[e * 3 + 2] * 64);
    packed[pos] = (unsigned)ei[e] | (cb << 18);
}

// per-layer bond-combo table
__global__ void k_ctab(const float* __restrict__ bemb, float* __restrict__ ctab) {
    int t = blockIdx.x * 256 + threadIdx.x;
    int cb = t >> 5, c = (t & 31) << 2;
    int a0 = cb & 7, a1 = (cb >> 3) & 7, a2 = cb >> 6;
    float4 b0 = *(const float4*)(bemb + (size_t)(0 * VBc + a0) * HH + c);
    float4 b1 = *(const float4*)(bemb + (size_t)(1 * VBc + a1) * HH + c);
    float4 b2 = *(const float4*)(bemb + (size_t)(2 * VBc + a2) * HH + c);
    float4 o = make_float4(b0.x + b1.x + b2.x, b0.y + b1.y + b2.y,
                           b0.z + b1.z + b2.z, b0.w + b1.w + b2.w);
    *(float4*)(ctab + (size_t)cb * HH + c) = o;
}

// per-layer folded BN tables
__global__ void k_prep(const float* __restrict__ b1, const float* __restrict__ g1,
                       const float* __restrict__ be1, const float* __restrict__ m1,
                       const float* __restrict__ v1,
                       const float* __restrict__ g3, const float* __restrict__ be3,
                       const float* __restrict__ m3, const float* __restrict__ v3,
                       float* __restrict__ ZA, float* __restrict__ ZB,
                       float* __restrict__ TA, float* __restrict__ TB,
                       float* __restrict__ S3) {
    int c = threadIdx.x;   // 256
    float s1 = g1[c] * rsqrtf(v1[c] + 1e-5f);
    ZA[c] = s1;
    ZB[c] = ((b1[c] - m1[c]) * s1 + be1[c]) * 0.0625f;
    float s3 = g3[c] * rsqrtf(v3[c] + 1e-5f);
    TA[c] = 16.f * s3;
    TB[c] = be3[c] - m3[c] * s3;
    S3[c] = s3;
}

// weight transpose: W [K][Nsrc] f32 -> Wt [N][K] fp16
__global__ void k_wt(const float* __restrict__ W, ushort* __restrict__ Wt, int lk, int Nsrc) {
    int o = blockIdx.x * 256 + threadIdx.x;
    int K = 1 << lk;
    int c = o >> lk, k = o & (K - 1);
    Wt[o] = f2h(W[(size_t)k * Nsrc + c]);
}

// CSR aggregation: agg[n] = (1/16) sum relu(16*(h16[src]+vn16[batch[src]])+ctab)
__global__ void k_agg(const ushort* __restrict__ h16, const ushort* __restrict__ vn16,
                      const int* __restrict__ batch,
                      const int* __restrict__ rowptr, const unsigned* __restrict__ packed,
                      const float* __restrict__ ctab, ushort* __restrict__ agg) {
    int n = blockIdx.x * 4 + (threadIdx.x >> 6);
    int lane = threadIdx.x & 63;
    int co = lane * 2;
    int beg = rowptr[n], end = rowptr[n + 1];
    float a0 = 0.f, a1 = 0.f;
    int i = beg;
    for (; i + 1 < end; i += 2) {
        unsigned p0 = packed[i], p1 = packed[i + 1];
        int s0 = p0 & 0x3FFFF, s1 = p1 & 0x3FFFF;
        int c0 = p0 >> 18, c1 = p1 >> 18;
        ushort2 u0 = *(const ushort2*)(h16 + (size_t)s0 * HH + co);
        ushort2 u1 = *(const ushort2*)(h16 + (size_t)s1 * HH + co);
        ushort2 w0 = *(const ushort2*)(vn16 + (size_t)batch[s0] * HH + co);
        ushort2 w1 = *(const ushort2*)(vn16 + (size_t)batch[s1] * HH + co);
        float2 t0 = *(const float2*)(ctab + (size_t)c0 * HH + co);
        float2 t1 = *(const float2*)(ctab + (size_t)c1 * HH + co);
        a0 += fmaxf(16.f * (h2f(u0.x) + h2f(w0.x)) + t0.x, 0.f)
            + fmaxf(16.f * (h2f(u1.x) + h2f(w1.x)) + t1.x, 0.f);
        a1 += fmaxf(16.f * (h2f(u0.y) + h2f(w0.y)) + t0.y, 0.f)
            + fmaxf(16.f * (h2f(u1.y) + h2f(w1.y)) + t1.y, 0.f);
    }
    if (i < end) {
        unsigned p = packed[i];
        int src = p & 0x3FFFF, cb = p >> 18;
        ushort2 u = *(const ushort2*)(h16 + (size_t)src * HH + co);
        ushort2 wv = *(const ushort2*)(vn16 + (size_t)batch[src] * HH + co);
        float2 ct = *(const float2*)(ctab + (size_t)cb * HH + co);
        a0 += fmaxf(16.f * (h2f(u.x) + h2f(wv.x)) + ct.x, 0.f);
        a1 += fmaxf(16.f * (h2f(u.y) + h2f(wv.y)) + ct.y, 0.f);
    }
    ushort2 o; o.x = f2h(a0 * 0.0625f); o.y = f2h(a1 * 0.0625f);
    *(ushort2*)(agg + (size_t)n * HH + co) = o;
}

// ============== mega-kernel: 64-row tile, 256 thr, 80 KB LDS -> 2 blocks/CU ==============
// XOR swizzle at 16B-block granularity: blk ^= (row & 7).
__global__ void __launch_bounds__(256, 2)
k_conv(ushort* __restrict__ h16, const ushort* __restrict__ agg,
       const ushort* __restrict__ W1t, const ushort* __restrict__ W2t,
       const ushort* __restrict__ W3t,
       const int* __restrict__ batch, const ushort* __restrict__ vn16,
       const float* __restrict__ vnW,
       const float* __restrict__ eps_ptr,
       const float* __restrict__ ZA, const float* __restrict__ ZB,
       const float* __restrict__ b2,
       const float* __restrict__ TA, const float* __restrict__ TB,
       float* __restrict__ pooled) {
    __shared__ ushort As[64][128];    // A/16, then h'/16   16 KB
    __shared__ ushort zs[64][256];    // z/16, then t       32 KB
    __shared__ ushort Wb[64][256];    // weight tiles       32 KB  (total 80 KB)
    ushort(*Wq)[128] = (ushort(*)[128]) & Wb[0][0];   // quarter view [64][128]
    const int tid = threadIdx.x;
    const int r0 = blockIdx.x * 64;
    const int w = tid >> 6, l = tid & 63, lr = l & 15, lg = l >> 4, lr7 = lr & 7;
    const float eps1 = 1.f + eps_ptr[0];
    f32x4 acc[4];

    // ---- stage A (wave-local rows): A/16 = eps1*(h16 + vn16) + agg16 ----
    {
        int row = tid >> 2, q = tid & 3, r7 = row & 7;
        int gg = batch[r0 + row];
        const ushort* hp = h16 + (size_t)(r0 + row) * HH;
        const ushort* vp = vn16 + (size_t)gg * HH;
        const ushort* ap = agg + (size_t)(r0 + row) * HH;
#pragma unroll
        for (int j4 = 0; j4 < 4; ++j4) {
            int c0 = q * 32 + j4 * 8;
            f16x8 hv = *(const f16x8*)(hp + c0);
            f16x8 vg = *(const f16x8*)(vp + c0);
            f16x8 ag = *(const f16x8*)(ap + c0);
            f16x8 o;
#pragma unroll
            for (int j = 0; j < 8; ++j)
                o[j] = (f16)(eps1 * ((float)hv[j] + (float)vg[j]) + (float)ag[j]);
            *(f16x8*)&As[row][((c0 >> 3) ^ r7) << 3] = o;
        }
    }

    // ---- phase A: z = relu(acc*ZA + ZB) /16 -> zs; W1 in 4 quarters ----
    for (int qt = 0; qt < 4; ++qt) {
        __syncthreads();
        {   // stage W1 quarter [64 cols][128 K]
            int c = tid >> 2, q = tid & 3, c7 = c & 7;
#pragma unroll
            for (int j4 = 0; j4 < 4; ++j4) {
                int blk = q * 4 + j4;
                *(f16x8*)&Wq[c][(blk ^ c7) << 3] =
                    *(const f16x8*)(W1t + (size_t)(qt * 64 + c) * 128 + blk * 8);
            }
        }
        __syncthreads();
#pragma unroll
        for (int fc = 0; fc < 4; ++fc) acc[fc] = (f32x4){0.f, 0.f, 0.f, 0.f};
#pragma unroll
        for (int k0 = 0; k0 < 4; ++k0) {
            int sb = ((k0 * 4 + lg) ^ lr7) << 3;
            f16x8 af = *(const f16x8*)&As[w * 16 + lr][sb];
#pragma unroll
            for (int fc = 0; fc < 4; ++fc) {
                f16x8 bf = *(const f16x8*)&Wq[fc * 16 + lr][sb];
                acc[fc] = __builtin_amdgcn_mfma_f32_16x16x32_f16(af, bf, acc[fc], 0, 0, 0);
            }
        }
#pragma unroll
        for (int fc = 0; fc < 4; ++fc) {
            int col = qt * 64 + fc * 16 + lr;
            float za = ZA[col], zb = ZB[col];
#pragma unroll
            for (int reg = 0; reg < 4; ++reg) {
                int rl = w * 16 + lg * 4 + reg;
                float zv = fmaxf(acc[fc][reg] * za + zb, 0.f);
                zs[rl][(((col >> 3) ^ (rl & 7)) << 3) | (col & 7)] = f2h(zv);
            }
        }
    }

    // ---- phase B: h' = acc*16 + b2 -> global h16 + As; W2 in 2 halves ----
    for (int ch = 0; ch < 2; ++ch) {
        __syncthreads();
        {   // stage W2 half [64 outcols][256 K]
            int c = tid >> 2, q = tid & 3, c7 = c & 7;
#pragma unroll
            for (int j8 = 0; j8 < 8; ++j8) {
                int blk = q * 8 + j8;
                *(f16x8*)&Wb[c][(blk ^ c7) << 3] =
                    *(const f16x8*)(W2t + (size_t)(ch * 64 + c) * 256 + blk * 8);
            }
        }
        __syncthreads();
#pragma unroll
        for (int fc = 0; fc < 4; ++fc) acc[fc] = (f32x4){0.f, 0.f, 0.f, 0.f};
#pragma unroll
        for (int k0 = 0; k0 < 8; ++k0) {
            int sb = ((k0 * 4 + lg) ^ lr7) << 3;
            f16x8 af = *(const f16x8*)&zs[w * 16 + lr][sb];
#pragma unroll
            for (int fc = 0; fc < 4; ++fc) {
                f16x8 bf = *(const f16x8*)&Wb[fc * 16 + lr][sb];
                acc[fc] = __builtin_amdgcn_mfma_f32_16x16x32_f16(af, bf, acc[fc], 0, 0, 0);
            }
        }
#pragma unroll
        for (int fc = 0; fc < 4; ++fc) {
            int col = ch * 64 + fc * 16 + lr;
            float bb = b2[col];
#pragma unroll
            for (int reg = 0; reg < 4; ++reg) {
                int rl = w * 16 + lg * 4 + reg;
                float hv = acc[fc][reg] * 16.f + bb;
                ushort hq = f2h(hv * 0.0625f);
                h16[(size_t)(r0 + rl) * HH + col] = hq;
                As[rl][(((col >> 3) ^ (rl & 7)) << 3) | (col & 7)] = hq;
            }
        }
    }

    // ---- phase C: t = relu(acc*TA + vnW' + TB) -> zs; W3 in 4 quarters ----
    for (int qt = 0; qt < 4; ++qt) {
        __syncthreads();
        {   // stage W3 quarter [64 cols][128 K]
            int c = tid >> 2, q = tid & 3, c7 = c & 7;
#pragma unroll
            for (int j4 = 0; j4 < 4; ++j4) {
                int blk = q * 4 + j4;
                *(f16x8*)&Wq[c][(blk ^ c7) << 3] =
                    *(const f16x8*)(W3t + (size_t)(qt * 64 + c) * 128 + blk * 8);
            }
        }
        __syncthreads();
#pragma unroll
        for (int fc = 0; fc < 4; ++fc) acc[fc] = (f32x4){0.f, 0.f, 0.f, 0.f};
#pragma unroll
        for (int k0 = 0; k0 < 4; ++k0) {
            int sb = ((k0 * 4 + lg) ^ lr7) << 3;
            f16x8 af = *(const f16x8*)&As[w * 16 + lr][sb];
#pragma unroll
            for (int fc = 0; fc < 4; ++fc) {
                f16x8 bf = *(const f16x8*)&Wq[fc * 16 + lr][sb];
                acc[fc] = __builtin_amdgcn_mfma_f32_16x16x32_f16(af, bf, acc[fc], 0, 0, 0);
            }
        }
        int rls[4], ggs[4];
#pragma unroll
        for (int reg = 0; reg < 4; ++reg) {
            rls[reg] = w * 16 + lg * 4 + reg;
            ggs[reg] = batch[r0 + rls[reg]];
        }
#pragma unroll
        for (int fc = 0; fc < 4; ++fc) {
            int colg = qt * 64 + fc * 16 + lr;
            float ta = TA[colg], tb = TB[colg];
#pragma unroll
            for (int reg = 0; reg < 4; ++reg) {
                int rl = rls[reg];
                float tv = fmaxf(acc[fc][reg] * ta + vnW[(size_t)ggs[reg] * 256 + colg] + tb, 0.f);
                zs[rl][(((colg >> 3) ^ (rl & 7)) << 3) | (colg & 7)] = f2h(tv);
            }
        }
    }
    __syncthreads();
    // ---- pool: 256 threads, col = tid, rows 0..63 run-length ----
    {
        int col = tid;
        float s = 0.f;
        int cur = batch[r0];
        for (int r = 0; r < 64; ++r) {
            int gg = batch[r0 + r];
            if (gg != cur) {
                atomicAdd(&pooled[(size_t)cur * 256 + col], s);
                s = 0.f; cur = gg;
            }
            s += h2f(zs[r][(((col >> 3) ^ (r & 7)) << 3) | (col & 7)]);
        }
        atomicAdd(&pooled[(size_t)cur * 256 + col], s);
    }
}

// ---------------- small f32 GEMM (GEMM3a, GEMM4) ----------------
enum { E_BIAS = 0, E_BNRELU = 1 };
template <int EMODE>
__global__ void __launch_bounds__(256)
gemm_k(const void* __restrict__ Av, const float* __restrict__ B,
       const float* __restrict__ bias,
       const float* __restrict__ g_, const float* __restrict__ b_,
       const float* __restrict__ m_, const float* __restrict__ v_,
       const float* __restrict__ scp,
       void* __restrict__ outv, int K, int Nc) {
    __shared__ float As[64][33];
    __shared__ float Bs[32][64];
    const int tid = threadIdx.x;
    const int row0 = blockIdx.x * 64;
    const int col0 = blockIdx.y * 64;
    float acc[4][4] = {};
    const int tx = tid & 15, ty = tid >> 4;
    for (int k0 = 0; k0 < K; k0 += 32) {
#pragma unroll
        for (int p = 0; p < 2; ++p) {
            int idx = p * 256 + tid;
            {
                int r = idx >> 3, c = (idx & 7) << 2;
                size_t aoff = (size_t)(row0 + r) * K + k0 + c;
                float4 va = *(const float4*)((const float*)Av + aoff);
                As[r][c + 0] = va.x; As[r][c + 1] = va.y;
                As[r][c + 2] = va.z; As[r][c + 3] = va.w;
            }
            {
                int kr = idx >> 4, cc = (idx & 15) << 2;
                *(float4*)&Bs[kr][cc] =
                    *(const float4*)(B + (size_t)(k0 + kr) * Nc + col0 + cc);
            }
        }
        __syncthreads();
#pragma unroll
        for (int k = 0; k < 32; ++k) {
            float4 bv = *(const float4*)&Bs[k][tx << 2];
            float a0 = As[ty * 4 + 0][k];
            float a1 = As[ty * 4 + 1][k];
            float a2 = As[ty * 4 + 2][k];
            float a3 = As[ty * 4 + 3][k];
            acc[0][0] += a0 * bv.x; acc[0][1] += a0 * bv.y; acc[0][2] += a0 * bv.z; acc[0][3] += a0 * bv.w;
            acc[1][0] += a1 * bv.x; acc[1][1] += a1 * bv.y; acc[1][2] += a1 * bv.z; acc[1][3] += a1 * bv.w;
            acc[2][0] += a2 * bv.x; acc[2][1] += a2 * bv.y; acc[2][2] += a2 * bv.z; acc[2][3] += a2 * bv.w;
            acc[3][0] += a3 * bv.x; acc[3][1] += a3 * bv.y; acc[3][2] += a3 * bv.z; acc[3][3] += a3 * bv.w;
        }
        __syncthreads();
    }
#pragma unroll
    for (int j = 0; j < 4; ++j) {
        int gr = row0 + ty * 4 + j;
        float vals[4];
#pragma unroll
        for (int lx = 0; lx < 4; ++lx) {
            int gc = col0 + (tx << 2) + lx;
            float val = acc[j][lx];
            if (EMODE == E_BIAS) {
                float v = val + bias[gc];
                if (scp) v *= scp[gc];
                vals[lx] = v;
            } else {
                float y = val + bias[gc];
                float s = g_[gc] * rsqrtf(v_[gc] + 1e-5f);
                y = (y - m_[gc]) * s + b_[gc];
                vals[lx] = fmaxf(y, 0.f);
            }
        }
        *(float4*)((float*)outv + (size_t)gr * Nc + col0 + (tx << 2)) =
            make_float4(vals[0], vals[1], vals[2], vals[3]);
    }
}

// ---------------- final head ----------------
__global__ void k_final(const float* __restrict__ vn, const float* __restrict__ pW1,
                        const float* __restrict__ pb1, const float* __restrict__ pW2,
                        const float* __restrict__ pb2, float* __restrict__ out) {
    int g = blockIdx.x;
    int j = threadIdx.x;
    __shared__ float vrow[HH];
    __shared__ float red[HH];
    vrow[j] = vn[(size_t)g * HH + j];
    __syncthreads();
    float acc = pb1[j];
    for (int k = 0; k < HH; ++k) acc = fmaf(vrow[k], pW1[k * HH + j], acc);
    red[j] = fmaxf(acc, 0.f) * pW2[j];
    __syncthreads();
    for (int s = 64; s > 0; s >>= 1) {
        if (j < s) red[j] += red[j + s];
        __syncthreads();
    }
    if (j == 0) out[g] = fminf(fmaxf(red[0] + pb2[0], 0.f), 50.f);
}

extern "C" void kernel_launch(void* const* d_in, const int* in_sizes, int n_in,
                              void* d_out, int out_size, void* d_ws, size_t ws_size,
                              hipStream_t stream) {
    const int*   x        = (const int*)  d_in[0];
    const int*   ei       = (const int*)  d_in[1];
    const int*   ea       = (const int*)  d_in[2];
    const int*   batch    = (const int*)  d_in[3];
    const float* atom_emb = (const float*)d_in[4];
    const float* vn_emb   = (const float*)d_in[5];
    const float* bond_emb = (const float*)d_in[6];
    const float* conv_eps = (const float*)d_in[7];
    const float* conv_W1  = (const float*)d_in[8];
    const float* conv_b1  = (const float*)d_in[9];
    const float* cbn_g    = (const float*)d_in[10];
    const float* cbn_b    = (const float*)d_in[11];
    const float* cbn_m    = (const float*)d_in[12];
    const float* cbn_v    = (const float*)d_in[13];
    const float* conv_W2  = (const float*)d_in[14];
    const float* conv_b2  = (const float*)d_in[15];
    const float* vn1_W    = (const float*)d_in[16];
    const float* vn1_b    = (const float*)d_in[17];
    const float* vn1_g    = (const float*)d_in[18];
    const float* vn1_be   = (const float*)d_in[19];
    const float* vn1_m    = (const float*)d_in[20];
    const float* vn1_v    = (const float*)d_in[21];
    const float* vn2_W    = (const float*)d_in[22];
    const float* vn2_b    = (const float*)d_in[23];
    const float* vn2_g    = (const float*)d_in[24];
    const float* vn2_be   = (const float*)d_in[25];
    const float* vn2_m    = (const float*)d_in[26];
    const float* vn2_v    = (const float*)d_in[27];
    const float* pW1      = (const float*)d_in[28];
    const float* pb1      = (const float*)d_in[29];
    const float* pW2      = (const float*)d_in[30];
    const float* pb2      = (const float*)d_in[31];

    // ---- workspace layout (~165 MB) ----
    char* base = (char*)d_ws;
    ushort*   h16    = (ushort*)base;                                 // NN*HH fp16 (state/16)
    ushort*   agg    = h16 + (size_t)NN * HH;                         // NN*HH fp16
    unsigned* packed = (unsigned*)(agg + (size_t)NN * HH);            // EE u32
    int*      rowptr = (int*)(packed + EE);                           // NN+4
    int*      fill   = rowptr + NN + 4;                               // NN
    float*    ctab   = (float*)(fill + NN);                           // 512*HH f32
    int*      sums   = (int*)(ctab + 512 * HH);                       // 256
    ushort*   W1t    = (ushort*)(sums + 256);                         // 256*128
    ushort*   W2t    = W1t + 256 * 128;                               // 128*256
    ushort*   W3t    = W2t + 128 * 256;                               // 256*128
    float*    ZA     = (float*)(W3t + 256 * 128);                     // 256
    float*    ZB     = ZA + 256;
    float*    TA     = ZB + 256;
    float*    TB     = TA + 256;
    float*    S3     = TB + 256;
    float*    vn     = S3 + 256;                                      // GG*HH f32
    ushort*   vn16   = (ushort*)(vn + (size_t)GG * HH);               // GG*HH fp16
    float*    vnW    = (float*)(vn16 + (size_t)GG * HH);              // GG*256
    float*    pooled = vnW + (size_t)GG * 256;                        // GG*256
    float*    out    = (float*)d_out;

    // ---- setup ----
    k_zero<<<256, 256, 0, stream>>>((float*)fill);
    k_hist<<<EE / 256, 256, 0, stream>>>(ei, fill);
    k_scan1<<<256, 256, 0, stream>>>(fill, rowptr, sums);
    k_scan2<<<1, 256, 0, stream>>>(sums);
    k_scan3<<<256, 256, 0, stream>>>(rowptr, sums, fill);
    k_scatter<<<EE / 256, 256, 0, stream>>>(ei, ea, fill, packed);
    k_atom<<<NN * 32 / 256, 256, 0, stream>>>(x, atom_emb, h16);
    k_init_vn<<<GG * HH / 4 / 256, 256, 0, stream>>>(vn_emb, vn);

    for (int i = 0; i < 4; ++i) {
        k_ctab<<<64, 256, 0, stream>>>(bond_emb + (size_t)i * FBc * VBc * HH, ctab);
        k_prep<<<1, 256, 0, stream>>>(
            conv_b1 + i * 256, cbn_g + i * 256, cbn_b + i * 256,
            cbn_m + i * 256, cbn_v + i * 256,
            vn1_g + i * 256, vn1_be + i * 256, vn1_m + i * 256, vn1_v + i * 256,
            ZA, ZB, TA, TB, S3);
        k_wt<<<128, 256, 0, stream>>>(conv_W1 + (size_t)i * HH * 256, W1t, 7, 256);
        k_wt<<<128, 256, 0, stream>>>(conv_W2 + (size_t)i * 256 * HH, W2t, 8, 128);
        k_wt<<<128, 256, 0, stream>>>(vn1_W + (size_t)i * 256 * 256 + 128 * 256, W3t, 7, 256);
        k_vn16<<<GG * HH / 4 / 256, 256, 0, stream>>>(vn, vn16);

        k_agg<<<NN / 4, 256, 0, stream>>>(h16, vn16, batch, rowptr, packed, ctab, agg);

        // GEMM3a: vnW' = (vn @ vn1_W[:128] + vn1_b) * s3
        {
            dim3 g3(GG / 64, 4);
            gemm_k<E_BIAS><<<g3, 256, 0, stream>>>(
                vn, vn1_W + (size_t)i * 256 * 256, vn1_b + i * 256,
                nullptr, nullptr, nullptr, nullptr, S3, vnW, HH, 256);
        }
        k_zero<<<GG * 256 / 4 / 256, 256, 0, stream>>>(pooled);

        // mega-kernel (64-row tiles, 2 blocks/CU)
        k_conv<<<NN / 64, 256, 0, stream>>>(
            h16, agg, W1t, W2t, W3t, batch, vn16, vnW, conv_eps + i,
            ZA, ZB, conv_b2 + i * HH, TA, TB, pooled);

        // GEMM4: vn = relu(bn(pooled @ vn2_W + vn2_b))
        {
            dim3 g4(GG / 64, 2);
            gemm_k<E_BNRELU><<<g4, 256, 0, stream>>>(
                pooled, vn2_W + (size_t)i * 256 * HH, vn2_b + i * HH,
                vn2_g + i * HH, vn2_be + i * HH, vn2_m + i * HH, vn2_v + i * HH,
                nullptr, vn, 256, HH);
        }
    }
    k_final<<<GG, 128, 0, stream>>>(vn, pW1, pb1, pW2, pb2, out);
}